// Round 12
// baseline (130.912 us; speedup 1.0000x reference)
//
#include <hip/hip_runtime.h>
#include <cmath>

#define DIM    64
#define MCODE  512
#define ROWS   131072
#define QELEMS 8388608   // 32*4096*64
#define BM     64        // rows per block
#define TPB    256
#define NBLK   (ROWS / BM)   // 2048

typedef _Float16 f16x8 __attribute__((ext_vector_type(8)));
typedef float    f32x4 __attribute__((ext_vector_type(4)));

#define COMP(v, c) ((c) == 0 ? (v).x : (c) == 1 ? (v).y : (c) == 2 ? (v).z : (v).w)

// ---------------- prep: cvec, error-bound constants, fp16 16x16-tiled + fp32-transposed codebook
__global__ __launch_bounds__(512) void vq_prep(const float* __restrict__ E,
                                               float* __restrict__ cvec,
                                               float* __restrict__ consts,  // [0]=max||ê||, [1]=max||e-ê||
                                               _Float16* __restrict__ Ebf,
                                               float* __restrict__ Et,      // [16 granules][512 codes] float4
                                               unsigned int* __restrict__ counts,
                                               double* __restrict__ lsum) {
    __shared__ float smax[512];
    const int m = threadIdx.x;            // 512 threads, 1 block
    counts[m] = 0u;
    if (m == 0) *lsum = 0.0;
    const float* e = E + (size_t)m * DIM;
    float r[8];
#pragma unroll
    for (int j = 0; j < 8; ++j) r[j] = e[j] * e[j];
#pragma unroll
    for (int i = 1; i < 8; ++i)
#pragma unroll
        for (int j = 0; j < 8; ++j) r[j] += e[8 * i + j] * e[8 * i + j];
    cvec[m] = ((r[0] + r[1]) + (r[2] + r[3])) + ((r[4] + r[5]) + (r[6] + r[7]));

    // transposed fp32 codebook for the coalesced rescue: Et[g*512 + code] (float4 units)
    float4* et = (float4*)Et;
#pragma unroll
    for (int g = 0; g < 16; ++g)
        et[g * 512 + m] = *(const float4*)(e + 4 * g);

    // fp16 codebook in 16x16x32 MFMA-A granule order:
    // code m: tile t=m>>4, c=m&15; k = km*32 + kg*8 + j  ->
    // granule index = ((t*2+km)*4 + kg)*16 + c   (main loop: granule (t*2+km)*64 + lane)
    const int t = m >> 4, c = m & 15;
    f16x8* dst = (f16x8*)Ebf;
    float en16 = 0.f, err2 = 0.f;
#pragma unroll
    for (int km = 0; km < 2; ++km)
#pragma unroll
        for (int kg = 0; kg < 4; ++kg) {
            f16x8 hv;
#pragma unroll
            for (int j = 0; j < 8; ++j) {
                const float ef = e[km * 32 + kg * 8 + j];
                const _Float16 h = (_Float16)ef;
                hv[j] = h;
                const float hf = (float)h;
                en16 = fmaf(hf, hf, en16);
                const float d = ef - hf;                 // exact (Sterbenz)
                err2 = fmaf(d, d, err2);
            }
            dst[((t * 2 + km) * 4 + kg) * 16 + c] = hv;
        }

    smax[m] = en16;
    __syncthreads();
    for (int s = 256; s > 0; s >>= 1) {
        if (m < s) smax[m] = fmaxf(smax[m], smax[m + s]);
        __syncthreads();
    }
    if (m == 0) consts[0] = sqrtf(smax[0]) * 1.0001f;
    __syncthreads();
    smax[m] = err2;
    __syncthreads();
    for (int s = 256; s > 0; s >>= 1) {
        if (m < s) smax[m] = fmaxf(smax[m], smax[m + s]);
        __syncthreads();
    }
    if (m == 0) consts[1] = sqrtf(smax[0]) * 1.0001f;
}

// ---------------- main: 16x16x32 f16-MFMA filter, wave = 16 rows x 512 codes
__global__ __launch_bounds__(TPB, 6) void vq_main(const float* __restrict__ X,
                                                  const float* __restrict__ E,
                                                  const float* __restrict__ cvec,
                                                  const float* __restrict__ consts,
                                                  const _Float16* __restrict__ Ebf,
                                                  const float* __restrict__ Et,
                                                  float* __restrict__ out,
                                                  unsigned int* __restrict__ counts,
                                                  double* __restrict__ lsum,
                                                  unsigned int* __restrict__ slab) {
    __shared__ int bidxs[BM];
    __shared__ unsigned int hist[MCODE];       // 2 KB
    __shared__ float scall[MCODE];             // 2 KB
    __shared__ int rlist[BM];
    __shared__ int rcount;
    __shared__ __align__(16) float4 xrl[16];   // rescue x-row stage
    __shared__ float rbd[TPB / 64];
    __shared__ int rbi[TPB / 64];
    __shared__ double red[TPB / 64];

    const int tid = threadIdx.x;
    const int w = tid >> 6;
    const int l = tid & 63;
    const int lg = l >> 4;      // k-group / code sub-group (0..3)
    const int lr = l & 15;      // row within wave tile

    for (int i = tid; i < MCODE; i += TPB) { hist[i] = 0u; scall[i] = cvec[i]; }
    if (tid == 0) rcount = 0;
    __syncthreads();

    // ---- x B-fragments: lane owns row w*16+lr, k = km*32 + lg*8 + {0..7}
    const float* Xb = X + (size_t)blockIdx.x * BM * DIM;
    const int xrow = w * 16 + lr;
    const float4* xp = (const float4*)(Xb + xrow * DIM);
    f16x8 xb[2];
    float xn2 = 0.f, dx2 = 0.f;
#pragma unroll
    for (int km = 0; km < 2; ++km) {
        const float4 a0 = xp[km * 8 + lg * 2 + 0];
        const float4 a1 = xp[km * 8 + lg * 2 + 1];
        f16x8 v;
        v[0] = (_Float16)a0.x; v[1] = (_Float16)a0.y; v[2] = (_Float16)a0.z; v[3] = (_Float16)a0.w;
        v[4] = (_Float16)a1.x; v[5] = (_Float16)a1.y; v[6] = (_Float16)a1.z; v[7] = (_Float16)a1.w;
        xb[km] = v;
        float hf, d;
        hf = (float)v[0]; d = a0.x - hf; dx2 = fmaf(d, d, dx2); xn2 = fmaf(a0.x, a0.x, xn2);
        hf = (float)v[1]; d = a0.y - hf; dx2 = fmaf(d, d, dx2); xn2 = fmaf(a0.y, a0.y, xn2);
        hf = (float)v[2]; d = a0.z - hf; dx2 = fmaf(d, d, dx2); xn2 = fmaf(a0.z, a0.z, xn2);
        hf = (float)v[3]; d = a0.w - hf; dx2 = fmaf(d, d, dx2); xn2 = fmaf(a0.w, a0.w, xn2);
        hf = (float)v[4]; d = a1.x - hf; dx2 = fmaf(d, d, dx2); xn2 = fmaf(a1.x, a1.x, xn2);
        hf = (float)v[5]; d = a1.y - hf; dx2 = fmaf(d, d, dx2); xn2 = fmaf(a1.y, a1.y, xn2);
        hf = (float)v[6]; d = a1.z - hf; dx2 = fmaf(d, d, dx2); xn2 = fmaf(a1.z, a1.z, xn2);
        hf = (float)v[7]; d = a1.w - hf; dx2 = fmaf(d, d, dx2); xn2 = fmaf(a1.w, a1.w, xn2);
    }
    // reduce across the 4 k-groups of the same row (lanes l, l^16, l^32, l^48)
    xn2 += __shfl_xor(xn2, 16, 64); xn2 += __shfl_xor(xn2, 32, 64);
    dx2 += __shfl_xor(dx2, 16, 64); dx2 += __shfl_xor(dx2, 32, 64);

    // per-lane scalar trackers (v = cm - 2*dot; nx cancels in m2-m1); st = step id
    float m1 = __builtin_inff(), m2 = __builtin_inff();
    int st = 0;

    const f16x8* Eg = (const f16x8*)Ebf;
#pragma unroll
    for (int t = 0; t < 32; ++t) {
        const f16x8 a0 = Eg[(t * 2 + 0) * 64 + l];        // fully coalesced, L1/L2-hot
        const f16x8 a1 = Eg[(t * 2 + 1) * 64 + l];
        const float4 cm = *(const float4*)(scall + t * 16 + lg * 4);   // LDS, conflict-free
        f32x4 acc = {0.f, 0.f, 0.f, 0.f};
        acc = __builtin_amdgcn_mfma_f32_16x16x32_f16(a0, xb[0], acc, 0, 0, 0);
        acc = __builtin_amdgcn_mfma_f32_16x16x32_f16(a1, xb[1], acc, 0, 0, 0);
#pragma unroll
        for (int r = 0; r < 4; ++r) {       // codes ascend with (t, r) within lane
            const float v = fmaf(-2.f, acc[r], COMP(cm, r));
            m2 = fminf(fmaxf(m1, v), m2);          // new second-min (m1<=m2 invariant)
            const bool b = v < m1;                 // strict < : first-min wins
            st = b ? (t * 4 + r) : st;
            m1 = b ? v : m1;
        }
    }
    int i1 = (st >> 2) * 16 + lg * 4 + (st & 3);

    // ---- merge the 4 lanes holding the same row (disjoint code subsets)
#pragma unroll
    for (int off = 16; off <= 32; off <<= 1) {
        const float od = __shfl_xor(m1, off, 64);
        const int oi = __shfl_xor(i1, off, 64);
        const float os = __shfl_xor(m2, off, 64);
        m2 = fminf(fminf(m2, os), fmaxf(m1, od));
        const bool tk = od < m1 || (od == m1 && oi < i1);
        m1 = tk ? od : m1; i1 = tk ? oi : i1;
    }

    // ---- tight rigorous ambiguity test + commit (lanes 0..15 own rows w*16+l)
    {
        const float2 cst = *(const float2*)consts;     // x: max||ê||, y: max||e-ê||
        const float dxn = sqrtf(dx2) * 1.02f;
        const float xn  = sqrtf(xn2) * 1.02f;
        const float delta = 2.1f * fmaf(dxn, cst.x, xn * cst.y) + 3.2e-7f * xn2 + 2e-6f;
        if (l < 16) {
            if (m2 - m1 > delta) {          // provably unique fp32 winner
                bidxs[xrow] = i1;
                atomicAdd(&hist[i1], 1u);
            } else {                        // ambiguous: exact cooperative rescan
                rlist[atomicAdd(&rcount, 1)] = xrow;
            }
        }
    }
    __syncthreads();

    // ---- cooperative rescue: whole block per row, 2 codes/thread, coalesced via Et
    for (int ri = 0; ri < rcount; ++ri) {
        const int row = rlist[ri];
        if (tid < 16) xrl[tid] = ((const float4*)(Xb + (size_t)row * DIM))[tid];
        __syncthreads();
        // exact ||x||^2, numpy pairwise 8-acc order (broadcast LDS reads)
        const float* xf = (const float*)xrl;
        float r[8];
#pragma unroll
        for (int j = 0; j < 8; ++j) { const float t = xf[j]; r[j] = t * t; }
#pragma unroll
        for (int i = 1; i < 8; ++i)
#pragma unroll
            for (int j = 0; j < 8; ++j) { const float t = xf[8 * i + j]; r[j] = fmaf(t, t, r[j]); }
        const float nxr = ((r[0] + r[1]) + (r[2] + r[3])) + ((r[4] + r[5]) + (r[6] + r[7]));

        float bmv = __builtin_inff(); int bix = 0;
        const float4* et = (const float4*)Et;
#pragma unroll
        for (int cc = 0; cc < 2; ++cc) {
            const int code = tid + 256 * cc;         // ascending within thread
            float dacc = 0.f;
#pragma unroll
            for (int g = 0; g < 16; ++g) {           // sequential k: exact reference order
                const float4 ev = et[g * 512 + code];   // lanes consecutive -> coalesced
                const float4 xv = xrl[g];
                dacc = fmaf(xv.x, ev.x, dacc);
                dacc = fmaf(xv.y, ev.y, dacc);
                dacc = fmaf(xv.z, ev.z, dacc);
                dacc = fmaf(xv.w, ev.w, dacc);
            }
            const float d2 = fmaf(-2.f, dacc, nxr) + scall[code];
            if (d2 < bmv) { bmv = d2; bix = code; }
        }
#pragma unroll
        for (int off = 1; off < 64; off <<= 1) {
            const float od = __shfl_xor(bmv, off, 64);
            const int oi = __shfl_xor(bix, off, 64);
            if (od < bmv || (od == bmv && oi < bix)) { bmv = od; bix = oi; }
        }
        if (l == 0) { rbd[w] = bmv; rbi[w] = bix; }
        __syncthreads();
        if (tid == 0) {
            float bb = rbd[0]; int ii = rbi[0];
#pragma unroll
            for (int wv = 1; wv < TPB / 64; ++wv)
                if (rbd[wv] < bb || (rbd[wv] == bb && rbi[wv] < ii)) { bb = rbd[wv]; ii = rbi[wv]; }
            bidxs[row] = ii;
            atomicAdd(&hist[ii], 1u);
        }
        __syncthreads();   // xrl/rbd reused next iteration
    }
    __syncthreads();

    // ---- epilogue: quantised_st + loss (x re-read coalesced, L2-hot; E L2-hot)
    float* outb = out + (size_t)blockIdx.x * BM * DIM;
    float ls = 0.f;
#pragma unroll
    for (int i = 0; i < 4; ++i) {
        const int gi = i * TPB + tid;
        const int row = gi >> 4;
        const int colL = gi & 15;
        const int bq = bidxs[row];
        const float4 qv = ((const float4*)E)[bq * 16 + colL];
        const float4 xv = ((const float4*)Xb)[gi];
        float4 o;
        { const float t = qv.x - xv.x; o.x = xv.x + t; const float dd = xv.x - qv.x; ls = fmaf(dd, dd, ls); }
        { const float t = qv.y - xv.y; o.y = xv.y + t; const float dd = xv.y - qv.y; ls = fmaf(dd, dd, ls); }
        { const float t = qv.z - xv.z; o.z = xv.z + t; const float dd = xv.z - qv.z; ls = fmaf(dd, dd, ls); }
        { const float t = qv.w - xv.w; o.w = xv.w + t; const float dd = xv.w - qv.w; ls = fmaf(dd, dd, ls); }
        ((float4*)outb)[gi] = o;
    }

#pragma unroll
    for (int off = 32; off > 0; off >>= 1) ls += __shfl_down(ls, off);
    if (l == 0) red[w] = (double)ls;
    __syncthreads();
    if (tid == 0) {
        double s = 0.0;
#pragma unroll
        for (int wv = 0; wv < TPB / 64; ++wv) s += red[wv];
        atomicAdd(lsum, s);
    }

    // ---- histogram flush: per-block slab (no atomics) or fallback atomic path
    if (slab) {
        unsigned int* sb = slab + (size_t)blockIdx.x * MCODE;
        for (int i = tid; i < MCODE; i += TPB) sb[i] = hist[i];
    } else {
        for (int i = tid; i < MCODE; i += TPB) {
            const unsigned int v = hist[i];
            if (v) atomicAdd(&counts[i], v);
        }
    }
}

// ---------------- mid reduce: 2048 slabs -> 64 partials (no atomics)
__global__ __launch_bounds__(512) void vq_mid(const unsigned int* __restrict__ slab,
                                              unsigned int* __restrict__ mid) {
    const int t = threadIdx.x, b = blockIdx.x;
    unsigned int s = 0;
#pragma unroll 4
    for (int j = 0; j < 32; ++j) s += slab[(size_t)(b * 32 + j) * MCODE + t];
    mid[b * MCODE + t] = s;
}

// ---------------- finalize: losses + perplexity
__global__ __launch_bounds__(512) void vq_fin(const unsigned int* __restrict__ cnt,
                                              int nsl,
                                              const double* __restrict__ lsum,
                                              float* __restrict__ out3) {
    __shared__ double sred[8];
    const int t = threadIdx.x;
    unsigned int c = 0;
    for (int b = 0; b < nsl; ++b) c += cnt[b * MCODE + t];
    const double avg = (double)c / (double)ROWS;
    double term = avg * log(avg + 1e-10);
#pragma unroll
    for (int off = 32; off > 0; off >>= 1) term += __shfl_down(term, off);
    const int lane = t & 63, wid = t >> 6;
    if (lane == 0) sred[wid] = term;
    __syncthreads();
    if (t == 0) {
        double s = 0.0;
#pragma unroll
        for (int w = 0; w < 8; ++w) s += sred[w];
        const float perp = (float)exp(-s);
        const float rl = (float)(*lsum / (double)QELEMS);
        out3[0] = 0.25f * rl;   // commitment_loss
        out3[1] = rl;           // codebook_loss
        out3[2] = perp;         // perplexity
    }
}

extern "C" void kernel_launch(void* const* d_in, const int* in_sizes, int n_in,
                              void* d_out, int out_size, void* d_ws, size_t ws_size,
                              hipStream_t stream) {
    const float* X = (const float*)d_in[0];       // [32,4096,64] fp32
    const float* E = (const float*)d_in[1];       // [512,64] fp32
    float* out = (float*)d_out;                   // 8388608 + 3 floats

    char* ws = (char*)d_ws;
    double* lsum          = (double*)(ws + 0);                 //    8 B
    unsigned int* counts  = (unsigned int*)(ws + 8);           // 2048 B (fallback)
    float* cvec           = (float*)(ws + 2056);               // 2048 B
    float* consts         = (float*)(ws + 4104);               //    8 B
    _Float16* Ebf         = (_Float16*)(ws + 4112);            // 65536 B, 16B-aligned
    float* Et             = (float*)(ws + 69648);              // 131072 B, 16B-aligned
    unsigned int* slab    = (unsigned int*)(ws + 200720);      // 2048*512*4 = 4 MB
    unsigned int* mid     = (unsigned int*)(ws + 200720 + 4194304);  // 64*512*4 = 128 KB
    const size_t NEED = 200720 + 4194304 + 131072;
    const bool big = ws_size >= NEED;

    vq_prep<<<1, MCODE, 0, stream>>>(E, cvec, consts, Ebf, Et, counts, lsum);
    vq_main<<<NBLK, TPB, 0, stream>>>(X, E, cvec, consts, Ebf, Et, out, counts, lsum,
                                      big ? slab : (unsigned int*)nullptr);
    if (big) {
        vq_mid<<<64, 512, 0, stream>>>(slab, mid);
        vq_fin<<<1, 512, 0, stream>>>(mid, 64, lsum, out + QELEMS);
    } else {
        vq_fin<<<1, 512, 0, stream>>>(counts, 1, lsum, out + QELEMS);
    }
}

// Round 13
// 103.761 us; speedup vs baseline: 1.2617x; 1.2617x over previous
//
#include <hip/hip_runtime.h>
#include <cmath>

#define DIM    64
#define MCODE  512
#define ROWS   131072
#define QELEMS 8388608   // 32*4096*64
#define BM     64        // rows per block
#define TPB    256
#define NBLK   (ROWS / BM)   // 2048

typedef _Float16 f16x8 __attribute__((ext_vector_type(8)));
typedef float    f32x4 __attribute__((ext_vector_type(4)));

#define COMP(v, c) ((c) == 0 ? (v).x : (c) == 1 ? (v).y : (c) == 2 ? (v).z : (v).w)

// ---------------- prep: cvec, error-bound constants, fp16 16x16-tiled + fp32-transposed codebook
__global__ __launch_bounds__(512) void vq_prep(const float* __restrict__ E,
                                               float* __restrict__ cvec,
                                               float* __restrict__ consts,  // [0]=max||ê||, [1]=max||e-ê||
                                               _Float16* __restrict__ Ebf,
                                               float* __restrict__ Et,      // [16 granules][512 codes] float4
                                               unsigned int* __restrict__ counts,
                                               double* __restrict__ lsum) {
    __shared__ float smax[512];
    const int m = threadIdx.x;            // 512 threads, 1 block
    counts[m] = 0u;
    if (m == 0) *lsum = 0.0;
    const float* e = E + (size_t)m * DIM;
    float r[8];
#pragma unroll
    for (int j = 0; j < 8; ++j) r[j] = e[j] * e[j];
#pragma unroll
    for (int i = 1; i < 8; ++i)
#pragma unroll
        for (int j = 0; j < 8; ++j) r[j] += e[8 * i + j] * e[8 * i + j];
    cvec[m] = ((r[0] + r[1]) + (r[2] + r[3])) + ((r[4] + r[5]) + (r[6] + r[7]));

    // transposed fp32 codebook for the coalesced rescue: Et[g*512 + code] (float4 units)
    float4* et = (float4*)Et;
#pragma unroll
    for (int g = 0; g < 16; ++g)
        et[g * 512 + m] = *(const float4*)(e + 4 * g);

    // fp16 codebook in 16x16x32 MFMA-A granule order:
    // code m: tile t=m>>4, c=m&15; k = km*32 + kg*8 + j  ->
    // granule index = ((t*2+km)*4 + kg)*16 + c   (main loop: granule (t*2+km)*64 + lane)
    const int t = m >> 4, c = m & 15;
    f16x8* dst = (f16x8*)Ebf;
    float en16 = 0.f, err2 = 0.f;
#pragma unroll
    for (int km = 0; km < 2; ++km)
#pragma unroll
        for (int kg = 0; kg < 4; ++kg) {
            f16x8 hv;
#pragma unroll
            for (int j = 0; j < 8; ++j) {
                const float ef = e[km * 32 + kg * 8 + j];
                const _Float16 h = (_Float16)ef;
                hv[j] = h;
                const float hf = (float)h;
                en16 = fmaf(hf, hf, en16);
                const float d = ef - hf;                 // exact (Sterbenz)
                err2 = fmaf(d, d, err2);
            }
            dst[((t * 2 + km) * 4 + kg) * 16 + c] = hv;
        }

    smax[m] = en16;
    __syncthreads();
    for (int s = 256; s > 0; s >>= 1) {
        if (m < s) smax[m] = fmaxf(smax[m], smax[m + s]);
        __syncthreads();
    }
    if (m == 0) consts[0] = sqrtf(smax[0]) * 1.0001f;
    __syncthreads();
    smax[m] = err2;
    __syncthreads();
    for (int s = 256; s > 0; s >>= 1) {
        if (m < s) smax[m] = fmaxf(smax[m], smax[m + s]);
        __syncthreads();
    }
    if (m == 0) consts[1] = sqrtf(smax[0]) * 1.0001f;
}

// ---------------- main: 16x16x32 f16-MFMA filter, wave = 16 rows x 512 codes
// launch_bounds (256,4): cap 128 VGPR — the only config that never spilled (R8/R10/R11).
__global__ __launch_bounds__(TPB, 4) void vq_main(const float* __restrict__ X,
                                                  const float* __restrict__ E,
                                                  const float* __restrict__ cvec,
                                                  const float* __restrict__ consts,
                                                  const _Float16* __restrict__ Ebf,
                                                  const float* __restrict__ Et,
                                                  float* __restrict__ out,
                                                  unsigned int* __restrict__ counts,
                                                  double* __restrict__ lsum,
                                                  unsigned int* __restrict__ slab) {
    __shared__ int bidxs[BM];
    __shared__ unsigned int hist[MCODE];       // 2 KB
    __shared__ float scall[MCODE];             // 2 KB
    __shared__ int rlist[BM];
    __shared__ int rcount;
    __shared__ __align__(16) float4 xrl[16];   // rescue x-row stage
    __shared__ float rbd[TPB / 64];
    __shared__ int rbi[TPB / 64];
    __shared__ double red[TPB / 64];

    const int tid = threadIdx.x;
    const int w = tid >> 6;
    const int l = tid & 63;
    const int lg = l >> 4;      // k-group / code sub-group (0..3)
    const int lr = l & 15;      // row within wave tile

    for (int i = tid; i < MCODE; i += TPB) { hist[i] = 0u; scall[i] = cvec[i]; }
    if (tid == 0) rcount = 0;
    __syncthreads();

    // ---- x B-fragments: lane owns row w*16+lr, k = km*32 + lg*8 + {0..7}
    const float* Xb = X + (size_t)blockIdx.x * BM * DIM;
    const int xrow = w * 16 + lr;
    const float4* xp = (const float4*)(Xb + xrow * DIM);
    f16x8 xb[2];
    float xn2 = 0.f, dx2 = 0.f;
#pragma unroll
    for (int km = 0; km < 2; ++km) {
        const float4 a0 = xp[km * 8 + lg * 2 + 0];
        const float4 a1 = xp[km * 8 + lg * 2 + 1];
        f16x8 v;
        v[0] = (_Float16)a0.x; v[1] = (_Float16)a0.y; v[2] = (_Float16)a0.z; v[3] = (_Float16)a0.w;
        v[4] = (_Float16)a1.x; v[5] = (_Float16)a1.y; v[6] = (_Float16)a1.z; v[7] = (_Float16)a1.w;
        xb[km] = v;
        float hf, d;
        hf = (float)v[0]; d = a0.x - hf; dx2 = fmaf(d, d, dx2); xn2 = fmaf(a0.x, a0.x, xn2);
        hf = (float)v[1]; d = a0.y - hf; dx2 = fmaf(d, d, dx2); xn2 = fmaf(a0.y, a0.y, xn2);
        hf = (float)v[2]; d = a0.z - hf; dx2 = fmaf(d, d, dx2); xn2 = fmaf(a0.z, a0.z, xn2);
        hf = (float)v[3]; d = a0.w - hf; dx2 = fmaf(d, d, dx2); xn2 = fmaf(a0.w, a0.w, xn2);
        hf = (float)v[4]; d = a1.x - hf; dx2 = fmaf(d, d, dx2); xn2 = fmaf(a1.x, a1.x, xn2);
        hf = (float)v[5]; d = a1.y - hf; dx2 = fmaf(d, d, dx2); xn2 = fmaf(a1.y, a1.y, xn2);
        hf = (float)v[6]; d = a1.z - hf; dx2 = fmaf(d, d, dx2); xn2 = fmaf(a1.z, a1.z, xn2);
        hf = (float)v[7]; d = a1.w - hf; dx2 = fmaf(d, d, dx2); xn2 = fmaf(a1.w, a1.w, xn2);
    }
    // reduce across the 4 k-groups of the same row (lanes l, l^16, l^32, l^48)
    xn2 += __shfl_xor(xn2, 16, 64); xn2 += __shfl_xor(xn2, 32, 64);
    dx2 += __shfl_xor(dx2, 16, 64); dx2 += __shfl_xor(dx2, 32, 64);

    // per-lane scalar trackers (v = cm - 2*dot; nx cancels in m2-m1); st = step id
    float m1 = __builtin_inff(), m2 = __builtin_inff();
    int st = 0;

    const f16x8* Eg = (const f16x8*)Ebf;
#pragma unroll 4
    for (int t = 0; t < 32; ++t) {
        const f16x8 a0 = Eg[(t * 2 + 0) * 64 + l];        // fully coalesced, L1/L2-hot
        const f16x8 a1 = Eg[(t * 2 + 1) * 64 + l];
        const float4 cm = *(const float4*)(scall + t * 16 + lg * 4);   // LDS, conflict-free
        f32x4 acc = {0.f, 0.f, 0.f, 0.f};
        acc = __builtin_amdgcn_mfma_f32_16x16x32_f16(a0, xb[0], acc, 0, 0, 0);
        acc = __builtin_amdgcn_mfma_f32_16x16x32_f16(a1, xb[1], acc, 0, 0, 0);
#pragma unroll
        for (int r = 0; r < 4; ++r) {       // codes ascend with (t, r) within lane
            const float v = fmaf(-2.f, acc[r], COMP(cm, r));
            m2 = fminf(fmaxf(m1, v), m2);          // new second-min (m1<=m2 invariant)
            const bool b = v < m1;                 // strict < : first-min wins
            st = b ? (t * 4 + r) : st;
            m1 = b ? v : m1;
        }
    }
    int i1 = (st >> 2) * 16 + lg * 4 + (st & 3);

    // ---- merge the 4 lanes holding the same row (disjoint code subsets)
#pragma unroll
    for (int off = 16; off <= 32; off <<= 1) {
        const float od = __shfl_xor(m1, off, 64);
        const int oi = __shfl_xor(i1, off, 64);
        const float os = __shfl_xor(m2, off, 64);
        m2 = fminf(fminf(m2, os), fmaxf(m1, od));
        const bool tk = od < m1 || (od == m1 && oi < i1);
        m1 = tk ? od : m1; i1 = tk ? oi : i1;
    }

    // ---- tight rigorous ambiguity test + commit (lanes 0..15 own rows w*16+l)
    {
        const float2 cst = *(const float2*)consts;     // x: max||ê||, y: max||e-ê||
        const float dxn = sqrtf(dx2) * 1.02f;
        const float xn  = sqrtf(xn2) * 1.02f;
        const float delta = 2.1f * fmaf(dxn, cst.x, xn * cst.y) + 3.2e-7f * xn2 + 2e-6f;
        if (l < 16) {
            if (m2 - m1 > delta) {          // provably unique fp32 winner
                bidxs[xrow] = i1;
                atomicAdd(&hist[i1], 1u);
            } else {                        // ambiguous: exact cooperative rescan
                rlist[atomicAdd(&rcount, 1)] = xrow;
            }
        }
    }
    __syncthreads();

    // ---- cooperative rescue: whole block per row, 2 codes/thread, coalesced via Et
    for (int ri = 0; ri < rcount; ++ri) {
        const int row = rlist[ri];
        if (tid < 16) xrl[tid] = ((const float4*)(Xb + (size_t)row * DIM))[tid];
        __syncthreads();
        // exact ||x||^2, numpy pairwise 8-acc order (broadcast LDS reads)
        const float* xf = (const float*)xrl;
        float r[8];
#pragma unroll
        for (int j = 0; j < 8; ++j) { const float t = xf[j]; r[j] = t * t; }
#pragma unroll
        for (int i = 1; i < 8; ++i)
#pragma unroll
            for (int j = 0; j < 8; ++j) { const float t = xf[8 * i + j]; r[j] = fmaf(t, t, r[j]); }
        const float nxr = ((r[0] + r[1]) + (r[2] + r[3])) + ((r[4] + r[5]) + (r[6] + r[7]));

        float bmv = __builtin_inff(); int bix = 0;
        const float4* et = (const float4*)Et;
#pragma unroll
        for (int cc = 0; cc < 2; ++cc) {
            const int code = tid + 256 * cc;         // ascending within thread
            float dacc = 0.f;
#pragma unroll
            for (int g = 0; g < 16; ++g) {           // sequential k: exact reference order
                const float4 ev = et[g * 512 + code];   // lanes consecutive -> coalesced
                const float4 xv = xrl[g];
                dacc = fmaf(xv.x, ev.x, dacc);
                dacc = fmaf(xv.y, ev.y, dacc);
                dacc = fmaf(xv.z, ev.z, dacc);
                dacc = fmaf(xv.w, ev.w, dacc);
            }
            const float d2 = fmaf(-2.f, dacc, nxr) + scall[code];
            if (d2 < bmv) { bmv = d2; bix = code; }
        }
#pragma unroll
        for (int off = 1; off < 64; off <<= 1) {
            const float od = __shfl_xor(bmv, off, 64);
            const int oi = __shfl_xor(bix, off, 64);
            if (od < bmv || (od == bmv && oi < bix)) { bmv = od; bix = oi; }
        }
        if (l == 0) { rbd[w] = bmv; rbi[w] = bix; }
        __syncthreads();
        if (tid == 0) {
            float bb = rbd[0]; int ii = rbi[0];
#pragma unroll
            for (int wv = 1; wv < TPB / 64; ++wv)
                if (rbd[wv] < bb || (rbd[wv] == bb && rbi[wv] < ii)) { bb = rbd[wv]; ii = rbi[wv]; }
            bidxs[row] = ii;
            atomicAdd(&hist[ii], 1u);
        }
        __syncthreads();   // xrl/rbd reused next iteration
    }
    __syncthreads();

    // ---- epilogue: quantised_st + loss (x re-read coalesced, L2-hot; E L2-hot)
    float* outb = out + (size_t)blockIdx.x * BM * DIM;
    float ls = 0.f;
#pragma unroll
    for (int i = 0; i < 4; ++i) {
        const int gi = i * TPB + tid;
        const int row = gi >> 4;
        const int colL = gi & 15;
        const int bq = bidxs[row];
        const float4 qv = ((const float4*)E)[bq * 16 + colL];
        const float4 xv = ((const float4*)Xb)[gi];
        float4 o;
        { const float t = qv.x - xv.x; o.x = xv.x + t; const float dd = xv.x - qv.x; ls = fmaf(dd, dd, ls); }
        { const float t = qv.y - xv.y; o.y = xv.y + t; const float dd = xv.y - qv.y; ls = fmaf(dd, dd, ls); }
        { const float t = qv.z - xv.z; o.z = xv.z + t; const float dd = xv.z - qv.z; ls = fmaf(dd, dd, ls); }
        { const float t = qv.w - xv.w; o.w = xv.w + t; const float dd = xv.w - qv.w; ls = fmaf(dd, dd, ls); }
        ((float4*)outb)[gi] = o;
    }

#pragma unroll
    for (int off = 32; off > 0; off >>= 1) ls += __shfl_down(ls, off);
    if (l == 0) red[w] = (double)ls;
    __syncthreads();
    if (tid == 0) {
        double s = 0.0;
#pragma unroll
        for (int wv = 0; wv < TPB / 64; ++wv) s += red[wv];
        atomicAdd(lsum, s);
    }

    // ---- histogram flush: per-block slab (no atomics) or fallback atomic path
    if (slab) {
        unsigned int* sb = slab + (size_t)blockIdx.x * MCODE;
        for (int i = tid; i < MCODE; i += TPB) sb[i] = hist[i];
    } else {
        for (int i = tid; i < MCODE; i += TPB) {
            const unsigned int v = hist[i];
            if (v) atomicAdd(&counts[i], v);
        }
    }
}

// ---------------- mid reduce: 2048 slabs -> 64 partials (no atomics)
__global__ __launch_bounds__(512) void vq_mid(const unsigned int* __restrict__ slab,
                                              unsigned int* __restrict__ mid) {
    const int t = threadIdx.x, b = blockIdx.x;
    unsigned int s = 0;
#pragma unroll 4
    for (int j = 0; j < 32; ++j) s += slab[(size_t)(b * 32 + j) * MCODE + t];
    mid[b * MCODE + t] = s;
}

// ---------------- finalize: losses + perplexity
__global__ __launch_bounds__(512) void vq_fin(const unsigned int* __restrict__ cnt,
                                              int nsl,
                                              const double* __restrict__ lsum,
                                              float* __restrict__ out3) {
    __shared__ double sred[8];
    const int t = threadIdx.x;
    unsigned int c = 0;
    for (int b = 0; b < nsl; ++b) c += cnt[b * MCODE + t];
    const double avg = (double)c / (double)ROWS;
    double term = avg * log(avg + 1e-10);
#pragma unroll
    for (int off = 32; off > 0; off >>= 1) term += __shfl_down(term, off);
    const int lane = t & 63, wid = t >> 6;
    if (lane == 0) sred[wid] = term;
    __syncthreads();
    if (t == 0) {
        double s = 0.0;
#pragma unroll
        for (int w = 0; w < 8; ++w) s += sred[w];
        const float perp = (float)exp(-s);
        const float rl = (float)(*lsum / (double)QELEMS);
        out3[0] = 0.25f * rl;   // commitment_loss
        out3[1] = rl;           // codebook_loss
        out3[2] = perp;         // perplexity
    }
}

extern "C" void kernel_launch(void* const* d_in, const int* in_sizes, int n_in,
                              void* d_out, int out_size, void* d_ws, size_t ws_size,
                              hipStream_t stream) {
    const float* X = (const float*)d_in[0];       // [32,4096,64] fp32
    const float* E = (const float*)d_in[1];       // [512,64] fp32
    float* out = (float*)d_out;                   // 8388608 + 3 floats

    char* ws = (char*)d_ws;
    double* lsum          = (double*)(ws + 0);                 //    8 B
    unsigned int* counts  = (unsigned int*)(ws + 8);           // 2048 B (fallback)
    float* cvec           = (float*)(ws + 2056);               // 2048 B
    float* consts         = (float*)(ws + 4104);               //    8 B
    _Float16* Ebf         = (_Float16*)(ws + 4112);            // 65536 B, 16B-aligned
    float* Et             = (float*)(ws + 69648);              // 131072 B, 16B-aligned
    unsigned int* slab    = (unsigned int*)(ws + 200720);      // 2048*512*4 = 4 MB
    unsigned int* mid     = (unsigned int*)(ws + 200720 + 4194304);  // 64*512*4 = 128 KB
    const size_t NEED = 200720 + 4194304 + 131072;
    const bool big = ws_size >= NEED;

    vq_prep<<<1, MCODE, 0, stream>>>(E, cvec, consts, Ebf, Et, counts, lsum);
    vq_main<<<NBLK, TPB, 0, stream>>>(X, E, cvec, consts, Ebf, Et, out, counts, lsum,
                                      big ? slab : (unsigned int*)nullptr);
    if (big) {
        vq_mid<<<64, 512, 0, stream>>>(slab, mid);
        vq_fin<<<1, 512, 0, stream>>>(mid, 64, lsum, out + QELEMS);
    } else {
        vq_fin<<<1, 512, 0, stream>>>(counts, 1, lsum, out + QELEMS);
    }
}

// Round 14
// 90.409 us; speedup vs baseline: 1.4480x; 1.1477x over previous
//
#include <hip/hip_runtime.h>
#include <cmath>

#define DIM    64
#define MCODE  512
#define ROWS   131072
#define QELEMS 8388608   // 32*4096*64
#define BM     64        // rows per block
#define TPB    256
#define NBLK   (ROWS / BM)   // 2048

typedef _Float16 f16x8 __attribute__((ext_vector_type(8)));
typedef float    f32x4 __attribute__((ext_vector_type(4)));

#define COMP(v, c) ((c) == 0 ? (v).x : (c) == 1 ? (v).y : (c) == 2 ? (v).z : (v).w)

// ---------------- prep: cvec, error-bound constants, fp16 16x16-tiled + fp32-transposed codebook
__global__ __launch_bounds__(512) void vq_prep(const float* __restrict__ E,
                                               float* __restrict__ cvec,
                                               float* __restrict__ consts,  // [0]=max||ê||, [1]=max||e-ê||
                                               _Float16* __restrict__ Ebf,
                                               float* __restrict__ Et,      // [16 granules][512 codes] float4
                                               unsigned int* __restrict__ counts,
                                               double* __restrict__ lsum) {
    __shared__ float smax[512];
    const int m = threadIdx.x;            // 512 threads, 1 block
    counts[m] = 0u;
    if (m == 0) *lsum = 0.0;
    const float* e = E + (size_t)m * DIM;
    float r[8];
#pragma unroll
    for (int j = 0; j < 8; ++j) r[j] = e[j] * e[j];
#pragma unroll
    for (int i = 1; i < 8; ++i)
#pragma unroll
        for (int j = 0; j < 8; ++j) r[j] += e[8 * i + j] * e[8 * i + j];
    cvec[m] = ((r[0] + r[1]) + (r[2] + r[3])) + ((r[4] + r[5]) + (r[6] + r[7]));

    // transposed fp32 codebook for the coalesced rescue: Et[g*512 + code] (float4 units)
    float4* et = (float4*)Et;
#pragma unroll
    for (int g = 0; g < 16; ++g)
        et[g * 512 + m] = *(const float4*)(e + 4 * g);

    // fp16 codebook in 16x16x32 MFMA-A granule order:
    // code m: tile t=m>>4, c=m&15; k = km*32 + kg*8 + j  ->
    // granule index = ((t*2+km)*4 + kg)*16 + c   (main loop: granule (t*2+km)*64 + lane)
    const int t = m >> 4, c = m & 15;
    f16x8* dst = (f16x8*)Ebf;
    float en16 = 0.f, err2 = 0.f;
#pragma unroll
    for (int km = 0; km < 2; ++km)
#pragma unroll
        for (int kg = 0; kg < 4; ++kg) {
            f16x8 hv;
#pragma unroll
            for (int j = 0; j < 8; ++j) {
                const float ef = e[km * 32 + kg * 8 + j];
                const _Float16 h = (_Float16)ef;
                hv[j] = h;
                const float hf = (float)h;
                en16 = fmaf(hf, hf, en16);
                const float d = ef - hf;                 // exact (Sterbenz)
                err2 = fmaf(d, d, err2);
            }
            dst[((t * 2 + km) * 4 + kg) * 16 + c] = hv;
        }

    smax[m] = en16;
    __syncthreads();
    for (int s = 256; s > 0; s >>= 1) {
        if (m < s) smax[m] = fmaxf(smax[m], smax[m + s]);
        __syncthreads();
    }
    if (m == 0) consts[0] = sqrtf(smax[0]) * 1.0001f;
    __syncthreads();
    smax[m] = err2;
    __syncthreads();
    for (int s = 256; s > 0; s >>= 1) {
        if (m < s) smax[m] = fmaxf(smax[m], smax[m + s]);
        __syncthreads();
    }
    if (m == 0) consts[1] = sqrtf(smax[0]) * 1.0001f;
}

// ---------------- main: 16x16x32 f16-MFMA filter, wave = 16 rows x 512 codes
// launch_bounds (256,1): VGPR cap 512 — allocator free, NO spill. (Every (256,>=4)
// build chose 64 VGPR per its occupancy heuristic and spilled ~8KB/wave: the
// ~60MB mystery WRITE_SIZE seen R8-R13.)
__global__ __launch_bounds__(TPB, 1) void vq_main(const float* __restrict__ X,
                                                  const float* __restrict__ E,
                                                  const float* __restrict__ cvec,
                                                  const float* __restrict__ consts,
                                                  const _Float16* __restrict__ Ebf,
                                                  const float* __restrict__ Et,
                                                  float* __restrict__ out,
                                                  unsigned int* __restrict__ counts,
                                                  double* __restrict__ lsum,
                                                  unsigned int* __restrict__ slab) {
    __shared__ int bidxs[BM];
    __shared__ unsigned int hist[MCODE];       // 2 KB
    __shared__ float scall[MCODE];             // 2 KB
    __shared__ int rlist[BM];
    __shared__ int rcount;
    __shared__ __align__(16) float4 xrl[16];   // rescue x-row stage
    __shared__ float rbd[TPB / 64];
    __shared__ int rbi[TPB / 64];
    __shared__ double red[TPB / 64];

    const int tid = threadIdx.x;
    const int w = tid >> 6;
    const int l = tid & 63;
    const int lg = l >> 4;      // k-group / code sub-group (0..3)
    const int lr = l & 15;      // row within wave tile

    for (int i = tid; i < MCODE; i += TPB) { hist[i] = 0u; scall[i] = cvec[i]; }
    if (tid == 0) rcount = 0;
    __syncthreads();

    // ---- x B-fragments: lane owns row w*16+lr, k = km*32 + lg*8 + {0..7}
    const float* Xb = X + (size_t)blockIdx.x * BM * DIM;
    const int xrow = w * 16 + lr;
    const float4* xp = (const float4*)(Xb + xrow * DIM);
    f16x8 xb[2];
    float xn2 = 0.f, dx2 = 0.f;
#pragma unroll
    for (int km = 0; km < 2; ++km) {
        const float4 a0 = xp[km * 8 + lg * 2 + 0];
        const float4 a1 = xp[km * 8 + lg * 2 + 1];
        f16x8 v;
        v[0] = (_Float16)a0.x; v[1] = (_Float16)a0.y; v[2] = (_Float16)a0.z; v[3] = (_Float16)a0.w;
        v[4] = (_Float16)a1.x; v[5] = (_Float16)a1.y; v[6] = (_Float16)a1.z; v[7] = (_Float16)a1.w;
        xb[km] = v;
        float hf, d;
        hf = (float)v[0]; d = a0.x - hf; dx2 = fmaf(d, d, dx2); xn2 = fmaf(a0.x, a0.x, xn2);
        hf = (float)v[1]; d = a0.y - hf; dx2 = fmaf(d, d, dx2); xn2 = fmaf(a0.y, a0.y, xn2);
        hf = (float)v[2]; d = a0.z - hf; dx2 = fmaf(d, d, dx2); xn2 = fmaf(a0.z, a0.z, xn2);
        hf = (float)v[3]; d = a0.w - hf; dx2 = fmaf(d, d, dx2); xn2 = fmaf(a0.w, a0.w, xn2);
        hf = (float)v[4]; d = a1.x - hf; dx2 = fmaf(d, d, dx2); xn2 = fmaf(a1.x, a1.x, xn2);
        hf = (float)v[5]; d = a1.y - hf; dx2 = fmaf(d, d, dx2); xn2 = fmaf(a1.y, a1.y, xn2);
        hf = (float)v[6]; d = a1.z - hf; dx2 = fmaf(d, d, dx2); xn2 = fmaf(a1.z, a1.z, xn2);
        hf = (float)v[7]; d = a1.w - hf; dx2 = fmaf(d, d, dx2); xn2 = fmaf(a1.w, a1.w, xn2);
    }
    // reduce across the 4 k-groups of the same row (lanes l, l^16, l^32, l^48)
    xn2 += __shfl_xor(xn2, 16, 64); xn2 += __shfl_xor(xn2, 32, 64);
    dx2 += __shfl_xor(dx2, 16, 64); dx2 += __shfl_xor(dx2, 32, 64);

    // per-lane scalar trackers (v = cm - 2*dot; nx cancels in m2-m1); st = step id
    float m1 = __builtin_inff(), m2 = __builtin_inff();
    int st = 0;

    const f16x8* Eg = (const f16x8*)Ebf;
#pragma unroll 4
    for (int t = 0; t < 32; ++t) {
        const f16x8 a0 = Eg[(t * 2 + 0) * 64 + l];        // fully coalesced, L1/L2-hot
        const f16x8 a1 = Eg[(t * 2 + 1) * 64 + l];
        const float4 cm = *(const float4*)(scall + t * 16 + lg * 4);   // LDS, conflict-free
        f32x4 acc = {0.f, 0.f, 0.f, 0.f};
        acc = __builtin_amdgcn_mfma_f32_16x16x32_f16(a0, xb[0], acc, 0, 0, 0);
        acc = __builtin_amdgcn_mfma_f32_16x16x32_f16(a1, xb[1], acc, 0, 0, 0);
#pragma unroll
        for (int r = 0; r < 4; ++r) {       // codes ascend with (t, r) within lane
            const float v = fmaf(-2.f, acc[r], COMP(cm, r));
            m2 = fminf(fmaxf(m1, v), m2);          // new second-min (m1<=m2 invariant)
            const bool b = v < m1;                 // strict < : first-min wins
            st = b ? (t * 4 + r) : st;
            m1 = b ? v : m1;
        }
    }
    int i1 = (st >> 2) * 16 + lg * 4 + (st & 3);

    // ---- merge the 4 lanes holding the same row (disjoint code subsets)
#pragma unroll
    for (int off = 16; off <= 32; off <<= 1) {
        const float od = __shfl_xor(m1, off, 64);
        const int oi = __shfl_xor(i1, off, 64);
        const float os = __shfl_xor(m2, off, 64);
        m2 = fminf(fminf(m2, os), fmaxf(m1, od));
        const bool tk = od < m1 || (od == m1 && oi < i1);
        m1 = tk ? od : m1; i1 = tk ? oi : i1;
    }

    // ---- tight rigorous ambiguity test + commit (lanes 0..15 own rows w*16+l)
    {
        const float2 cst = *(const float2*)consts;     // x: max||ê||, y: max||e-ê||
        const float dxn = sqrtf(dx2) * 1.02f;
        const float xn  = sqrtf(xn2) * 1.02f;
        const float delta = 2.1f * fmaf(dxn, cst.x, xn * cst.y) + 3.2e-7f * xn2 + 2e-6f;
        if (l < 16) {
            if (m2 - m1 > delta) {          // provably unique fp32 winner
                bidxs[xrow] = i1;
                atomicAdd(&hist[i1], 1u);
            } else {                        // ambiguous: exact cooperative rescan
                rlist[atomicAdd(&rcount, 1)] = xrow;
            }
        }
    }
    __syncthreads();

    // ---- cooperative rescue: whole block per row, 2 codes/thread, coalesced via Et
    for (int ri = 0; ri < rcount; ++ri) {
        const int row = rlist[ri];
        if (tid < 16) xrl[tid] = ((const float4*)(Xb + (size_t)row * DIM))[tid];
        __syncthreads();
        // exact ||x||^2, numpy pairwise 8-acc order (broadcast LDS reads)
        const float* xf = (const float*)xrl;
        float r[8];
#pragma unroll
        for (int j = 0; j < 8; ++j) { const float t = xf[j]; r[j] = t * t; }
#pragma unroll
        for (int i = 1; i < 8; ++i)
#pragma unroll
            for (int j = 0; j < 8; ++j) { const float t = xf[8 * i + j]; r[j] = fmaf(t, t, r[j]); }
        const float nxr = ((r[0] + r[1]) + (r[2] + r[3])) + ((r[4] + r[5]) + (r[6] + r[7]));

        float bmv = __builtin_inff(); int bix = 0;
        const float4* et = (const float4*)Et;
#pragma unroll
        for (int cc = 0; cc < 2; ++cc) {
            const int code = tid + 256 * cc;         // ascending within thread
            float dacc = 0.f;
#pragma unroll
            for (int g = 0; g < 16; ++g) {           // sequential k: exact reference order
                const float4 ev = et[g * 512 + code];   // lanes consecutive -> coalesced
                const float4 xv = xrl[g];
                dacc = fmaf(xv.x, ev.x, dacc);
                dacc = fmaf(xv.y, ev.y, dacc);
                dacc = fmaf(xv.z, ev.z, dacc);
                dacc = fmaf(xv.w, ev.w, dacc);
            }
            const float d2 = fmaf(-2.f, dacc, nxr) + scall[code];
            if (d2 < bmv) { bmv = d2; bix = code; }
        }
#pragma unroll
        for (int off = 1; off < 64; off <<= 1) {
            const float od = __shfl_xor(bmv, off, 64);
            const int oi = __shfl_xor(bix, off, 64);
            if (od < bmv || (od == bmv && oi < bix)) { bmv = od; bix = oi; }
        }
        if (l == 0) { rbd[w] = bmv; rbi[w] = bix; }
        __syncthreads();
        if (tid == 0) {
            float bb = rbd[0]; int ii = rbi[0];
#pragma unroll
            for (int wv = 1; wv < TPB / 64; ++wv)
                if (rbd[wv] < bb || (rbd[wv] == bb && rbi[wv] < ii)) { bb = rbd[wv]; ii = rbi[wv]; }
            bidxs[row] = ii;
            atomicAdd(&hist[ii], 1u);
        }
        __syncthreads();   // xrl/rbd reused next iteration
    }
    __syncthreads();

    // ---- epilogue: quantised_st + loss (x re-read coalesced, L3-hot; E L2-hot)
    float* outb = out + (size_t)blockIdx.x * BM * DIM;
    float ls = 0.f;
#pragma unroll
    for (int i = 0; i < 4; ++i) {
        const int gi = i * TPB + tid;
        const int row = gi >> 4;
        const int colL = gi & 15;
        const int bq = bidxs[row];
        const float4 qv = ((const float4*)E)[bq * 16 + colL];
        const float4 xv = ((const float4*)Xb)[gi];
        float4 o;
        { const float t = qv.x - xv.x; o.x = xv.x + t; const float dd = xv.x - qv.x; ls = fmaf(dd, dd, ls); }
        { const float t = qv.y - xv.y; o.y = xv.y + t; const float dd = xv.y - qv.y; ls = fmaf(dd, dd, ls); }
        { const float t = qv.z - xv.z; o.z = xv.z + t; const float dd = xv.z - qv.z; ls = fmaf(dd, dd, ls); }
        { const float t = qv.w - xv.w; o.w = xv.w + t; const float dd = xv.w - qv.w; ls = fmaf(dd, dd, ls); }
        ((float4*)outb)[gi] = o;
    }

#pragma unroll
    for (int off = 32; off > 0; off >>= 1) ls += __shfl_down(ls, off);
    if (l == 0) red[w] = (double)ls;
    __syncthreads();
    if (tid == 0) {
        double s = 0.0;
#pragma unroll
        for (int wv = 0; wv < TPB / 64; ++wv) s += red[wv];
        atomicAdd(lsum, s);
    }

    // ---- histogram flush: per-block slab (no atomics) or fallback atomic path
    if (slab) {
        unsigned int* sb = slab + (size_t)blockIdx.x * MCODE;
        for (int i = tid; i < MCODE; i += TPB) sb[i] = hist[i];
    } else {
        for (int i = tid; i < MCODE; i += TPB) {
            const unsigned int v = hist[i];
            if (v) atomicAdd(&counts[i], v);
        }
    }
}

// ---------------- mid reduce: 2048 slabs -> 64 partials (no atomics)
__global__ __launch_bounds__(512) void vq_mid(const unsigned int* __restrict__ slab,
                                              unsigned int* __restrict__ mid) {
    const int t = threadIdx.x, b = blockIdx.x;
    unsigned int s = 0;
#pragma unroll 4
    for (int j = 0; j < 32; ++j) s += slab[(size_t)(b * 32 + j) * MCODE + t];
    mid[b * MCODE + t] = s;
}

// ---------------- finalize: losses + perplexity
__global__ __launch_bounds__(512) void vq_fin(const unsigned int* __restrict__ cnt,
                                              int nsl,
                                              const double* __restrict__ lsum,
                                              float* __restrict__ out3) {
    __shared__ double sred[8];
    const int t = threadIdx.x;
    unsigned int c = 0;
    for (int b = 0; b < nsl; ++b) c += cnt[b * MCODE + t];
    const double avg = (double)c / (double)ROWS;
    double term = avg * log(avg + 1e-10);
#pragma unroll
    for (int off = 32; off > 0; off >>= 1) term += __shfl_down(term, off);
    const int lane = t & 63, wid = t >> 6;
    if (lane == 0) sred[wid] = term;
    __syncthreads();
    if (t == 0) {
        double s = 0.0;
#pragma unroll
        for (int w = 0; w < 8; ++w) s += sred[w];
        const float perp = (float)exp(-s);
        const float rl = (float)(*lsum / (double)QELEMS);
        out3[0] = 0.25f * rl;   // commitment_loss
        out3[1] = rl;           // codebook_loss
        out3[2] = perp;         // perplexity
    }
}

extern "C" void kernel_launch(void* const* d_in, const int* in_sizes, int n_in,
                              void* d_out, int out_size, void* d_ws, size_t ws_size,
                              hipStream_t stream) {
    const float* X = (const float*)d_in[0];       // [32,4096,64] fp32
    const float* E = (const float*)d_in[1];       // [512,64] fp32
    float* out = (float*)d_out;                   // 8388608 + 3 floats

    char* ws = (char*)d_ws;
    double* lsum          = (double*)(ws + 0);                 //    8 B
    unsigned int* counts  = (unsigned int*)(ws + 8);           // 2048 B (fallback)
    float* cvec           = (float*)(ws + 2056);               // 2048 B
    float* consts         = (float*)(ws + 4104);               //    8 B
    _Float16* Ebf         = (_Float16*)(ws + 4112);            // 65536 B, 16B-aligned
    float* Et             = (float*)(ws + 69648);              // 131072 B, 16B-aligned
    unsigned int* slab    = (unsigned int*)(ws + 200720);      // 2048*512*4 = 4 MB
    unsigned int* mid     = (unsigned int*)(ws + 200720 + 4194304);  // 64*512*4 = 128 KB
    const size_t NEED = 200720 + 4194304 + 131072;
    const bool big = ws_size >= NEED;

    vq_prep<<<1, MCODE, 0, stream>>>(E, cvec, consts, Ebf, Et, counts, lsum);
    vq_main<<<NBLK, TPB, 0, stream>>>(X, E, cvec, consts, Ebf, Et, out, counts, lsum,
                                      big ? slab : (unsigned int*)nullptr);
    if (big) {
        vq_mid<<<64, 512, 0, stream>>>(slab, mid);
        vq_fin<<<1, 512, 0, stream>>>(mid, 64, lsum, out + QELEMS);
    } else {
        vq_fin<<<1, 512, 0, stream>>>(counts, 1, lsum, out + QELEMS);
    }
}

// Round 15
// 81.823 us; speedup vs baseline: 1.5999x; 1.1049x over previous
//
#include <hip/hip_runtime.h>
#include <cmath>

#define DIM    64
#define MCODE  512
#define ROWS   131072
#define QELEMS 8388608   // 32*4096*64
#define BM     64        // rows per block
#define TPB    256
#define NBLK   (ROWS / BM)   // 2048

typedef _Float16 f16x8 __attribute__((ext_vector_type(8)));
typedef float    f32x4 __attribute__((ext_vector_type(4)));

#define COMP(v, c) ((c) == 0 ? (v).x : (c) == 1 ? (v).y : (c) == 2 ? (v).z : (v).w)

// async global->LDS, 16B per lane; LDS dest = wave-uniform base + lane*16
__device__ __forceinline__ void async16(void* l, const void* g) {
    __builtin_amdgcn_global_load_lds(
        (const __attribute__((address_space(1))) unsigned int*)g,
        (__attribute__((address_space(3))) unsigned int*)l, 16, 0, 0);
}

// ---------------- prep: cvec, error-bound constants, fp16 16x16-tiled + fp32-transposed codebook
__global__ __launch_bounds__(512) void vq_prep(const float* __restrict__ E,
                                               float* __restrict__ cvec,
                                               float* __restrict__ consts,  // [0]=max||ê||, [1]=max||e-ê||
                                               _Float16* __restrict__ Ebf,
                                               float* __restrict__ Et,      // [16 granules][512 codes] float4
                                               unsigned int* __restrict__ counts,
                                               double* __restrict__ lsum) {
    __shared__ float smax[512];
    const int m = threadIdx.x;            // 512 threads, 1 block
    counts[m] = 0u;
    if (m == 0) *lsum = 0.0;
    const float* e = E + (size_t)m * DIM;
    float r[8];
#pragma unroll
    for (int j = 0; j < 8; ++j) r[j] = e[j] * e[j];
#pragma unroll
    for (int i = 1; i < 8; ++i)
#pragma unroll
        for (int j = 0; j < 8; ++j) r[j] += e[8 * i + j] * e[8 * i + j];
    cvec[m] = ((r[0] + r[1]) + (r[2] + r[3])) + ((r[4] + r[5]) + (r[6] + r[7]));

    // transposed fp32 codebook for the coalesced rescue: Et[g*512 + code] (float4 units)
    float4* et = (float4*)Et;
#pragma unroll
    for (int g = 0; g < 16; ++g)
        et[g * 512 + m] = *(const float4*)(e + 4 * g);

    // fp16 codebook in 16x16x32 MFMA-A granule order:
    // code m: tile t=m>>4, c=m&15; k = km*32 + kg*8 + j  ->
    // granule index = ((t*2+km)*4 + kg)*16 + c
    const int t = m >> 4, c = m & 15;
    f16x8* dst = (f16x8*)Ebf;
    float en16 = 0.f, err2 = 0.f;
#pragma unroll
    for (int km = 0; km < 2; ++km)
#pragma unroll
        for (int kg = 0; kg < 4; ++kg) {
            f16x8 hv;
#pragma unroll
            for (int j = 0; j < 8; ++j) {
                const float ef = e[km * 32 + kg * 8 + j];
                const _Float16 h = (_Float16)ef;
                hv[j] = h;
                const float hf = (float)h;
                en16 = fmaf(hf, hf, en16);
                const float d = ef - hf;                 // exact (Sterbenz)
                err2 = fmaf(d, d, err2);
            }
            dst[((t * 2 + km) * 4 + kg) * 16 + c] = hv;
        }

    smax[m] = en16;
    __syncthreads();
    for (int s = 256; s > 0; s >>= 1) {
        if (m < s) smax[m] = fmaxf(smax[m], smax[m + s]);
        __syncthreads();
    }
    if (m == 0) consts[0] = sqrtf(smax[0]) * 1.0001f;
    __syncthreads();
    smax[m] = err2;
    __syncthreads();
    for (int s = 256; s > 0; s >>= 1) {
        if (m < s) smax[m] = fmaxf(smax[m], smax[m + s]);
        __syncthreads();
    }
    if (m == 0) consts[1] = sqrtf(smax[0]) * 1.0001f;
}

// ---------------- main: 16x16x32 f16-MFMA filter, wave = 16 rows x 512 codes
// Ebf staged in LDS by 32KB halves (12-cyc ds_read replaces ~200-cyc L2 hits;
// 4x less L2 traffic). launch_bounds (256,1): allocator free -> no spill (R14).
__global__ __launch_bounds__(TPB, 1) void vq_main(const float* __restrict__ X,
                                                  const float* __restrict__ E,
                                                  const float* __restrict__ cvec,
                                                  const float* __restrict__ consts,
                                                  const _Float16* __restrict__ Ebf,
                                                  const float* __restrict__ Et,
                                                  float* __restrict__ out,
                                                  unsigned int* __restrict__ counts,
                                                  double* __restrict__ lsum,
                                                  unsigned int* __restrict__ slab) {
    __shared__ __align__(16) _Float16 ebf[256 * DIM];   // 32 KB: one half of codes
    __shared__ int bidxs[BM];
    __shared__ unsigned int hist[MCODE];       // 2 KB
    __shared__ float scall[MCODE];             // 2 KB
    __shared__ int rlist[BM];
    __shared__ int rcount;
    __shared__ __align__(16) float4 xrl[16];   // rescue x-row stage
    __shared__ float rbd[TPB / 64];
    __shared__ int rbi[TPB / 64];
    __shared__ double red[TPB / 64];

    const int tid = threadIdx.x;
    const int w = tid >> 6;
    const int l = tid & 63;
    const int lg = l >> 4;      // k-group / code sub-group (0..3)
    const int lr = l & 15;      // row within wave tile

    // ---- issue phase-0 staging first (overlaps x-frag loads below)
#pragma unroll
    for (int i = 0; i < 8; ++i)
        async16(((f16x8*)ebf) + i * TPB + w * 64, (const f16x8*)Ebf + i * TPB + tid);

    for (int i = tid; i < MCODE; i += TPB) { hist[i] = 0u; scall[i] = cvec[i]; }
    if (tid == 0) rcount = 0;

    // ---- x B-fragments: lane owns row w*16+lr, k = km*32 + lg*8 + {0..7}
    const float* Xb = X + (size_t)blockIdx.x * BM * DIM;
    const int xrow = w * 16 + lr;
    const float4* xp = (const float4*)(Xb + xrow * DIM);
    f16x8 xb[2];
    float xn2 = 0.f, dx2 = 0.f;
#pragma unroll
    for (int km = 0; km < 2; ++km) {
        const float4 a0 = xp[km * 8 + lg * 2 + 0];
        const float4 a1 = xp[km * 8 + lg * 2 + 1];
        f16x8 v;
        v[0] = (_Float16)a0.x; v[1] = (_Float16)a0.y; v[2] = (_Float16)a0.z; v[3] = (_Float16)a0.w;
        v[4] = (_Float16)a1.x; v[5] = (_Float16)a1.y; v[6] = (_Float16)a1.z; v[7] = (_Float16)a1.w;
        xb[km] = v;
        float hf, d;
        hf = (float)v[0]; d = a0.x - hf; dx2 = fmaf(d, d, dx2); xn2 = fmaf(a0.x, a0.x, xn2);
        hf = (float)v[1]; d = a0.y - hf; dx2 = fmaf(d, d, dx2); xn2 = fmaf(a0.y, a0.y, xn2);
        hf = (float)v[2]; d = a0.z - hf; dx2 = fmaf(d, d, dx2); xn2 = fmaf(a0.z, a0.z, xn2);
        hf = (float)v[3]; d = a0.w - hf; dx2 = fmaf(d, d, dx2); xn2 = fmaf(a0.w, a0.w, xn2);
        hf = (float)v[4]; d = a1.x - hf; dx2 = fmaf(d, d, dx2); xn2 = fmaf(a1.x, a1.x, xn2);
        hf = (float)v[5]; d = a1.y - hf; dx2 = fmaf(d, d, dx2); xn2 = fmaf(a1.y, a1.y, xn2);
        hf = (float)v[6]; d = a1.z - hf; dx2 = fmaf(d, d, dx2); xn2 = fmaf(a1.z, a1.z, xn2);
        hf = (float)v[7]; d = a1.w - hf; dx2 = fmaf(d, d, dx2); xn2 = fmaf(a1.w, a1.w, xn2);
    }
    // reduce across the 4 k-groups of the same row (lanes l, l^16, l^32, l^48)
    xn2 += __shfl_xor(xn2, 16, 64); xn2 += __shfl_xor(xn2, 32, 64);
    dx2 += __shfl_xor(dx2, 16, 64); dx2 += __shfl_xor(dx2, 32, 64);

    // per-lane scalar trackers (v = cm - 2*dot; nx cancels in m2-m1); st = step id
    float m1 = __builtin_inff(), m2 = __builtin_inff();
    int st = 0;

    const f16x8* eb = (const f16x8*)ebf;
    for (int h = 0; h < 2; ++h) {
        if (h) {
            __syncthreads();   // all waves done reading half 0
#pragma unroll
            for (int i = 0; i < 8; ++i)
                async16(((f16x8*)ebf) + i * TPB + w * 64,
                        (const f16x8*)Ebf + 2048 + i * TPB + tid);
        }
        __syncthreads();       // staged half h ready (drains vmcnt)
#pragma unroll 4
        for (int tt = 0; tt < 16; ++tt) {
            const int t = h * 16 + tt;
            const f16x8 a0 = eb[tt * 128 + l];            // lane-consecutive b128: conflict-free
            const f16x8 a1 = eb[tt * 128 + 64 + l];
            const float4 cm = *(const float4*)(scall + t * 16 + lg * 4);
            f32x4 acc = {0.f, 0.f, 0.f, 0.f};
            acc = __builtin_amdgcn_mfma_f32_16x16x32_f16(a0, xb[0], acc, 0, 0, 0);
            acc = __builtin_amdgcn_mfma_f32_16x16x32_f16(a1, xb[1], acc, 0, 0, 0);
#pragma unroll
            for (int r = 0; r < 4; ++r) {   // codes ascend with (t, r) within lane
                const float v = fmaf(-2.f, acc[r], COMP(cm, r));
                m2 = __builtin_amdgcn_fmed3f(m1, v, m2);   // second-min (m1<=m2 invariant)
                const bool b = v < m1;                     // strict < : first-min wins
                st = b ? (t * 4 + r) : st;
                m1 = b ? v : m1;
            }
        }
    }
    int i1 = (st >> 2) * 16 + lg * 4 + (st & 3);

    // ---- merge the 4 lanes holding the same row (disjoint code subsets)
#pragma unroll
    for (int off = 16; off <= 32; off <<= 1) {
        const float od = __shfl_xor(m1, off, 64);
        const int oi = __shfl_xor(i1, off, 64);
        const float os = __shfl_xor(m2, off, 64);
        m2 = fminf(fminf(m2, os), fmaxf(m1, od));
        const bool tk = od < m1 || (od == m1 && oi < i1);
        m1 = tk ? od : m1; i1 = tk ? oi : i1;
    }

    // ---- tight rigorous ambiguity test + commit (lanes 0..15 own rows w*16+l)
    {
        const float2 cst = *(const float2*)consts;     // x: max||ê||, y: max||e-ê||
        const float dxn = sqrtf(dx2) * 1.02f;
        const float xn  = sqrtf(xn2) * 1.02f;
        const float delta = 2.1f * fmaf(dxn, cst.x, xn * cst.y) + 3.2e-7f * xn2 + 2e-6f;
        if (l < 16) {
            if (m2 - m1 > delta) {          // provably unique fp32 winner
                bidxs[xrow] = i1;
                atomicAdd(&hist[i1], 1u);
            } else {                        // ambiguous: exact cooperative rescan
                rlist[atomicAdd(&rcount, 1)] = xrow;
            }
        }
    }
    __syncthreads();

    // ---- cooperative rescue: whole block per row, 2 codes/thread, coalesced via Et
    for (int ri = 0; ri < rcount; ++ri) {
        const int row = rlist[ri];
        if (tid < 16) xrl[tid] = ((const float4*)(Xb + (size_t)row * DIM))[tid];
        __syncthreads();
        // exact ||x||^2, numpy pairwise 8-acc order (broadcast LDS reads)
        const float* xf = (const float*)xrl;
        float r[8];
#pragma unroll
        for (int j = 0; j < 8; ++j) { const float t = xf[j]; r[j] = t * t; }
#pragma unroll
        for (int i = 1; i < 8; ++i)
#pragma unroll
            for (int j = 0; j < 8; ++j) { const float t = xf[8 * i + j]; r[j] = fmaf(t, t, r[j]); }
        const float nxr = ((r[0] + r[1]) + (r[2] + r[3])) + ((r[4] + r[5]) + (r[6] + r[7]));

        float bmv = __builtin_inff(); int bix = 0;
        const float4* et = (const float4*)Et;
#pragma unroll
        for (int cc = 0; cc < 2; ++cc) {
            const int code = tid + 256 * cc;         // ascending within thread
            float dacc = 0.f;
#pragma unroll
            for (int g = 0; g < 16; ++g) {           // sequential k: exact reference order
                const float4 ev = et[g * 512 + code];   // lanes consecutive -> coalesced
                const float4 xv = xrl[g];
                dacc = fmaf(xv.x, ev.x, dacc);
                dacc = fmaf(xv.y, ev.y, dacc);
                dacc = fmaf(xv.z, ev.z, dacc);
                dacc = fmaf(xv.w, ev.w, dacc);
            }
            const float d2 = fmaf(-2.f, dacc, nxr) + scall[code];
            if (d2 < bmv) { bmv = d2; bix = code; }
        }
#pragma unroll
        for (int off = 1; off < 64; off <<= 1) {
            const float od = __shfl_xor(bmv, off, 64);
            const int oi = __shfl_xor(bix, off, 64);
            if (od < bmv || (od == bmv && oi < bix)) { bmv = od; bix = oi; }
        }
        if (l == 0) { rbd[w] = bmv; rbi[w] = bix; }
        __syncthreads();
        if (tid == 0) {
            float bb = rbd[0]; int ii = rbi[0];
#pragma unroll
            for (int wv = 1; wv < TPB / 64; ++wv)
                if (rbd[wv] < bb || (rbd[wv] == bb && rbi[wv] < ii)) { bb = rbd[wv]; ii = rbi[wv]; }
            bidxs[row] = ii;
            atomicAdd(&hist[ii], 1u);
        }
        __syncthreads();   // xrl/rbd reused next iteration
    }
    __syncthreads();

    // ---- epilogue: quantised_st + loss (x re-read coalesced, L3-hot; E L2-hot)
    float* outb = out + (size_t)blockIdx.x * BM * DIM;
    float ls = 0.f;
#pragma unroll
    for (int i = 0; i < 4; ++i) {
        const int gi = i * TPB + tid;
        const int row = gi >> 4;
        const int colL = gi & 15;
        const int bq = bidxs[row];
        const float4 qv = ((const float4*)E)[bq * 16 + colL];
        const float4 xv = ((const float4*)Xb)[gi];
        float4 o;
        { const float t = qv.x - xv.x; o.x = xv.x + t; const float dd = xv.x - qv.x; ls = fmaf(dd, dd, ls); }
        { const float t = qv.y - xv.y; o.y = xv.y + t; const float dd = xv.y - qv.y; ls = fmaf(dd, dd, ls); }
        { const float t = qv.z - xv.z; o.z = xv.z + t; const float dd = xv.z - qv.z; ls = fmaf(dd, dd, ls); }
        { const float t = qv.w - xv.w; o.w = xv.w + t; const float dd = xv.w - qv.w; ls = fmaf(dd, dd, ls); }
        ((float4*)outb)[gi] = o;
    }

#pragma unroll
    for (int off = 32; off > 0; off >>= 1) ls += __shfl_down(ls, off);
    if (l == 0) red[w] = (double)ls;
    __syncthreads();
    if (tid == 0) {
        double s = 0.0;
#pragma unroll
        for (int wv = 0; wv < TPB / 64; ++wv) s += red[wv];
        atomicAdd(lsum, s);
    }

    // ---- histogram flush: per-block slab (no atomics) or fallback atomic path
    if (slab) {
        unsigned int* sb = slab + (size_t)blockIdx.x * MCODE;
        for (int i = tid; i < MCODE; i += TPB) sb[i] = hist[i];
    } else {
        for (int i = tid; i < MCODE; i += TPB) {
            const unsigned int v = hist[i];
            if (v) atomicAdd(&counts[i], v);
        }
    }
}

// ---------------- mid reduce: 2048 slabs -> 64 partials (no atomics)
__global__ __launch_bounds__(512) void vq_mid(const unsigned int* __restrict__ slab,
                                              unsigned int* __restrict__ mid) {
    const int t = threadIdx.x, b = blockIdx.x;
    unsigned int s = 0;
#pragma unroll 4
    for (int j = 0; j < 32; ++j) s += slab[(size_t)(b * 32 + j) * MCODE + t];
    mid[b * MCODE + t] = s;
}

// ---------------- finalize: losses + perplexity
__global__ __launch_bounds__(512) void vq_fin(const unsigned int* __restrict__ cnt,
                                              int nsl,
                                              const double* __restrict__ lsum,
                                              float* __restrict__ out3) {
    __shared__ double sred[8];
    const int t = threadIdx.x;
    unsigned int c = 0;
    for (int b = 0; b < nsl; ++b) c += cnt[b * MCODE + t];
    const double avg = (double)c / (double)ROWS;
    double term = avg * log(avg + 1e-10);
#pragma unroll
    for (int off = 32; off > 0; off >>= 1) term += __shfl_down(term, off);
    const int lane = t & 63, wid = t >> 6;
    if (lane == 0) sred[wid] = term;
    __syncthreads();
    if (t == 0) {
        double s = 0.0;
#pragma unroll
        for (int w = 0; w < 8; ++w) s += sred[w];
        const float perp = (float)exp(-s);
        const float rl = (float)(*lsum / (double)QELEMS);
        out3[0] = 0.25f * rl;   // commitment_loss
        out3[1] = rl;           // codebook_loss
        out3[2] = perp;         // perplexity
    }
}

extern "C" void kernel_launch(void* const* d_in, const int* in_sizes, int n_in,
                              void* d_out, int out_size, void* d_ws, size_t ws_size,
                              hipStream_t stream) {
    const float* X = (const float*)d_in[0];       // [32,4096,64] fp32
    const float* E = (const float*)d_in[1];       // [512,64] fp32
    float* out = (float*)d_out;                   // 8388608 + 3 floats

    char* ws = (char*)d_ws;
    double* lsum          = (double*)(ws + 0);                 //    8 B
    unsigned int* counts  = (unsigned int*)(ws + 8);           // 2048 B (fallback)
    float* cvec           = (float*)(ws + 2056);               // 2048 B
    float* consts         = (float*)(ws + 4104);               //    8 B
    _Float16* Ebf         = (_Float16*)(ws + 4112);            // 65536 B, 16B-aligned
    float* Et             = (float*)(ws + 69648);              // 131072 B, 16B-aligned
    unsigned int* slab    = (unsigned int*)(ws + 200720);      // 2048*512*4 = 4 MB
    unsigned int* mid     = (unsigned int*)(ws + 200720 + 4194304);  // 64*512*4 = 128 KB
    const size_t NEED = 200720 + 4194304 + 131072;
    const bool big = ws_size >= NEED;

    vq_prep<<<1, MCODE, 0, stream>>>(E, cvec, consts, Ebf, Et, counts, lsum);
    vq_main<<<NBLK, TPB, 0, stream>>>(X, E, cvec, consts, Ebf, Et, out, counts, lsum,
                                      big ? slab : (unsigned int*)nullptr);
    if (big) {
        vq_mid<<<64, 512, 0, stream>>>(slab, mid);
        vq_fin<<<1, 512, 0, stream>>>(mid, 64, lsum, out + QELEMS);
    } else {
        vq_fin<<<1, 512, 0, stream>>>(counts, 1, lsum, out + QELEMS);
    }
}

// Round 16
// 68.595 us; speedup vs baseline: 1.9085x; 1.1928x over previous
//
#include <hip/hip_runtime.h>
#include <cmath>

#define DIM    64
#define MCODE  512
#define ROWS   131072
#define QELEMS 8388608   // 32*4096*64
#define BM     256       // rows per block (4 tiles of 64)
#define TPB    256
#define NBLK   (ROWS / BM)   // 512 -> 2 blocks/CU, all co-resident (LDS cap 4/CU)

typedef _Float16 f16x8 __attribute__((ext_vector_type(8)));
typedef float    f32x4 __attribute__((ext_vector_type(4)));

#define COMP(v, c) ((c) == 0 ? (v).x : (c) == 1 ? (v).y : (c) == 2 ? (v).z : (v).w)

// async global->LDS, 16B per lane; LDS dest = wave-uniform base + lane*16
__device__ __forceinline__ void async16(void* l, const void* g) {
    __builtin_amdgcn_global_load_lds(
        (const __attribute__((address_space(1))) unsigned int*)g,
        (__attribute__((address_space(3))) unsigned int*)l, 16, 0, 0);
}

// ---------------- prep: cvec, error-bound constants, fp16 16x16-tiled + fp32-transposed codebook
__global__ __launch_bounds__(512) void vq_prep(const float* __restrict__ E,
                                               float* __restrict__ cvec,
                                               float* __restrict__ consts,  // [0]=max||ê||, [1]=max||e-ê||
                                               _Float16* __restrict__ Ebf,
                                               float* __restrict__ Et,      // [16 granules][512 codes] float4
                                               unsigned int* __restrict__ counts,
                                               double* __restrict__ lsum) {
    __shared__ float sA[8], sB[8];
    const int m = threadIdx.x;            // 512 threads, 1 block
    counts[m] = 0u;
    if (m == 0) *lsum = 0.0;
    const float* e = E + (size_t)m * DIM;
    float r[8];
#pragma unroll
    for (int j = 0; j < 8; ++j) r[j] = e[j] * e[j];
#pragma unroll
    for (int i = 1; i < 8; ++i)
#pragma unroll
        for (int j = 0; j < 8; ++j) r[j] += e[8 * i + j] * e[8 * i + j];
    cvec[m] = ((r[0] + r[1]) + (r[2] + r[3])) + ((r[4] + r[5]) + (r[6] + r[7]));

    // transposed fp32 codebook for the coalesced rescue: Et[g*512 + code] (float4 units)
    float4* et = (float4*)Et;
#pragma unroll
    for (int g = 0; g < 16; ++g)
        et[g * 512 + m] = *(const float4*)(e + 4 * g);

    // fp16 codebook in 16x16x32 MFMA-A granule order:
    // code m: tile t=m>>4, c=m&15; k = km*32 + kg*8 + j  ->
    // granule index = ((t*2+km)*4 + kg)*16 + c
    const int t = m >> 4, c = m & 15;
    f16x8* dst = (f16x8*)Ebf;
    float en16 = 0.f, err2 = 0.f;
#pragma unroll
    for (int km = 0; km < 2; ++km)
#pragma unroll
        for (int kg = 0; kg < 4; ++kg) {
            f16x8 hv;
#pragma unroll
            for (int j = 0; j < 8; ++j) {
                const float ef = e[km * 32 + kg * 8 + j];
                const _Float16 h = (_Float16)ef;
                hv[j] = h;
                const float hf = (float)h;
                en16 = fmaf(hf, hf, en16);
                const float d = ef - hf;                 // exact (Sterbenz)
                err2 = fmaf(d, d, err2);
            }
            dst[((t * 2 + km) * 4 + kg) * 16 + c] = hv;
        }

    // wave-level max reduce (1 barrier instead of 18)
#pragma unroll
    for (int off = 1; off < 64; off <<= 1) {
        en16 = fmaxf(en16, __shfl_xor(en16, off, 64));
        err2 = fmaxf(err2, __shfl_xor(err2, off, 64));
    }
    if ((m & 63) == 0) { sA[m >> 6] = en16; sB[m >> 6] = err2; }
    __syncthreads();
    if (m == 0) {
        float a = sA[0], b = sB[0];
#pragma unroll
        for (int wv = 1; wv < 8; ++wv) { a = fmaxf(a, sA[wv]); b = fmaxf(b, sB[wv]); }
        consts[0] = sqrtf(a) * 1.0001f;
        consts[1] = sqrtf(b) * 1.0001f;
    }
}

// ---------------- main: 16x16x32 f16-MFMA filter; block = 256 rows (4 tiles), wave = 16 rows/tile.
// Each 32KB staged half serves all 4 tiles (staging traffic /4); 512 blocks = 2/CU, all co-resident.
__global__ __launch_bounds__(TPB, 1) void vq_main(const float* __restrict__ X,
                                                  const float* __restrict__ E,
                                                  const float* __restrict__ cvec,
                                                  const float* __restrict__ consts,
                                                  const _Float16* __restrict__ Ebf,
                                                  const float* __restrict__ Et,
                                                  float* __restrict__ out,
                                                  unsigned int* __restrict__ counts,
                                                  double* __restrict__ lsum,
                                                  unsigned int* __restrict__ slab) {
    __shared__ __align__(16) _Float16 ebf[256 * DIM];   // 32 KB: one half of codes
    __shared__ int bidxs[BM];                  // 1 KB
    __shared__ unsigned int hist[MCODE];       // 2 KB
    __shared__ float scall[MCODE];             // 2 KB
    __shared__ int rlist[BM];                  // 1 KB
    __shared__ int rcount;
    __shared__ __align__(16) float4 xrl[16];   // rescue x-row stage
    __shared__ float rbd[TPB / 64];
    __shared__ int rbi[TPB / 64];
    __shared__ double red[TPB / 64];

    const int tid = threadIdx.x;
    const int w = tid >> 6;
    const int l = tid & 63;
    const int lg = l >> 4;      // k-group / code sub-group (0..3)
    const int lr = l & 15;      // row within wave tile

    // ---- issue half-0 staging first (overlaps init + x-frag loads)
#pragma unroll
    for (int i = 0; i < 8; ++i)
        async16(((f16x8*)ebf) + i * TPB + w * 64, (const f16x8*)Ebf + i * TPB + tid);

    for (int i = tid; i < MCODE; i += TPB) { hist[i] = 0u; scall[i] = cvec[i]; }
    if (tid == 0) rcount = 0;
    __syncthreads();   // staging drained (vmcnt 0), hist/scall ready

    const float* Xb = X + (size_t)blockIdx.x * BM * DIM;
    const f16x8* eb = (const f16x8*)ebf;

    float m1a[4], m2a[4], xn2a[4], dx2a[4];
    int sta[4];

    // =============== half 0 : tiles 0..3, t = 0..15 ===============
#pragma unroll
    for (int rt = 0; rt < 4; ++rt) {
        const int xrow = rt * 64 + w * 16 + lr;
        const float4* xp = (const float4*)(Xb + xrow * DIM);
        f16x8 xb[2];
        float xn2 = 0.f, dx2 = 0.f;
#pragma unroll
        for (int km = 0; km < 2; ++km) {
            const float4 a0 = xp[km * 8 + lg * 2 + 0];
            const float4 a1 = xp[km * 8 + lg * 2 + 1];
            f16x8 v;
            v[0] = (_Float16)a0.x; v[1] = (_Float16)a0.y; v[2] = (_Float16)a0.z; v[3] = (_Float16)a0.w;
            v[4] = (_Float16)a1.x; v[5] = (_Float16)a1.y; v[6] = (_Float16)a1.z; v[7] = (_Float16)a1.w;
            xb[km] = v;
            float hf, d;
            hf = (float)v[0]; d = a0.x - hf; dx2 = fmaf(d, d, dx2); xn2 = fmaf(a0.x, a0.x, xn2);
            hf = (float)v[1]; d = a0.y - hf; dx2 = fmaf(d, d, dx2); xn2 = fmaf(a0.y, a0.y, xn2);
            hf = (float)v[2]; d = a0.z - hf; dx2 = fmaf(d, d, dx2); xn2 = fmaf(a0.z, a0.z, xn2);
            hf = (float)v[3]; d = a0.w - hf; dx2 = fmaf(d, d, dx2); xn2 = fmaf(a0.w, a0.w, xn2);
            hf = (float)v[4]; d = a1.x - hf; dx2 = fmaf(d, d, dx2); xn2 = fmaf(a1.x, a1.x, xn2);
            hf = (float)v[5]; d = a1.y - hf; dx2 = fmaf(d, d, dx2); xn2 = fmaf(a1.y, a1.y, xn2);
            hf = (float)v[6]; d = a1.z - hf; dx2 = fmaf(d, d, dx2); xn2 = fmaf(a1.z, a1.z, xn2);
            hf = (float)v[7]; d = a1.w - hf; dx2 = fmaf(d, d, dx2); xn2 = fmaf(a1.w, a1.w, xn2);
        }
        xn2 += __shfl_xor(xn2, 16, 64); xn2 += __shfl_xor(xn2, 32, 64);
        dx2 += __shfl_xor(dx2, 16, 64); dx2 += __shfl_xor(dx2, 32, 64);
        xn2a[rt] = xn2; dx2a[rt] = dx2;

        float m1 = __builtin_inff(), m2 = __builtin_inff();
        int st = 0;
#pragma unroll 4
        for (int tt = 0; tt < 16; ++tt) {
            const f16x8 a0 = eb[tt * 128 + l];        // lane-consecutive b128: conflict-free
            const f16x8 a1 = eb[tt * 128 + 64 + l];
            const float4 cm = *(const float4*)(scall + tt * 16 + lg * 4);
            f32x4 acc = {0.f, 0.f, 0.f, 0.f};
            acc = __builtin_amdgcn_mfma_f32_16x16x32_f16(a0, xb[0], acc, 0, 0, 0);
            acc = __builtin_amdgcn_mfma_f32_16x16x32_f16(a1, xb[1], acc, 0, 0, 0);
#pragma unroll
            for (int r = 0; r < 4; ++r) {   // codes ascend with (t, r) within lane
                const float v = fmaf(-2.f, acc[r], COMP(cm, r));
                m2 = __builtin_amdgcn_fmed3f(m1, v, m2);   // second-min (m1<=m2 invariant)
                const bool b = v < m1;                     // strict < : first-min wins
                st = b ? (tt * 4 + r) : st;
                m1 = b ? v : m1;
            }
        }
        m1a[rt] = m1; m2a[rt] = m2; sta[rt] = st;
    }

    // =============== stage half 1 ===============
    __syncthreads();   // all waves done reading half 0
#pragma unroll
    for (int i = 0; i < 8; ++i)
        async16(((f16x8*)ebf) + i * TPB + w * 64, (const f16x8*)Ebf + 2048 + i * TPB + tid);
    __syncthreads();   // half 1 staged (drains vmcnt)

    // =============== half 1 : tiles 0..3, t = 16..31 ===============
#pragma unroll
    for (int rt = 0; rt < 4; ++rt) {
        const int xrow = rt * 64 + w * 16 + lr;
        const float4* xp = (const float4*)(Xb + xrow * DIM);
        f16x8 xb[2];
#pragma unroll
        for (int km = 0; km < 2; ++km) {       // reload (L1/L3-hot), conversions only
            const float4 a0 = xp[km * 8 + lg * 2 + 0];
            const float4 a1 = xp[km * 8 + lg * 2 + 1];
            f16x8 v;
            v[0] = (_Float16)a0.x; v[1] = (_Float16)a0.y; v[2] = (_Float16)a0.z; v[3] = (_Float16)a0.w;
            v[4] = (_Float16)a1.x; v[5] = (_Float16)a1.y; v[6] = (_Float16)a1.z; v[7] = (_Float16)a1.w;
            xb[km] = v;
        }
        float m1 = m1a[rt], m2 = m2a[rt];
        int st = sta[rt];
#pragma unroll 4
        for (int tt = 0; tt < 16; ++tt) {
            const int t = 16 + tt;
            const f16x8 a0 = eb[tt * 128 + l];
            const f16x8 a1 = eb[tt * 128 + 64 + l];
            const float4 cm = *(const float4*)(scall + t * 16 + lg * 4);
            f32x4 acc = {0.f, 0.f, 0.f, 0.f};
            acc = __builtin_amdgcn_mfma_f32_16x16x32_f16(a0, xb[0], acc, 0, 0, 0);
            acc = __builtin_amdgcn_mfma_f32_16x16x32_f16(a1, xb[1], acc, 0, 0, 0);
#pragma unroll
            for (int r = 0; r < 4; ++r) {
                const float v = fmaf(-2.f, acc[r], COMP(cm, r));
                m2 = __builtin_amdgcn_fmed3f(m1, v, m2);
                const bool b = v < m1;
                st = b ? (t * 4 + r) : st;
                m1 = b ? v : m1;
            }
        }
        m1a[rt] = m1; m2a[rt] = m2; sta[rt] = st;
    }

    // =============== merge + commit per tile ===============
    const float2 cst = *(const float2*)consts;     // x: max||ê||, y: max||e-ê||
#pragma unroll
    for (int rt = 0; rt < 4; ++rt) {
        float m1 = m1a[rt], m2 = m2a[rt];
        int i1 = (sta[rt] >> 2) * 16 + lg * 4 + (sta[rt] & 3);
        // merge the 4 lanes holding the same row (disjoint code subsets)
#pragma unroll
        for (int off = 16; off <= 32; off <<= 1) {
            const float od = __shfl_xor(m1, off, 64);
            const int oi = __shfl_xor(i1, off, 64);
            const float os = __shfl_xor(m2, off, 64);
            m2 = fminf(fminf(m2, os), fmaxf(m1, od));
            const bool tk = od < m1 || (od == m1 && oi < i1);
            m1 = tk ? od : m1; i1 = tk ? oi : i1;
        }
        // tight rigorous ambiguity test + commit (lanes 0..15 own rows)
        const float dxn = sqrtf(dx2a[rt]) * 1.02f;
        const float xn  = sqrtf(xn2a[rt]) * 1.02f;
        const float delta = 2.1f * fmaf(dxn, cst.x, xn * cst.y) + 3.2e-7f * xn2a[rt] + 2e-6f;
        if (l < 16) {
            const int xrow = rt * 64 + w * 16 + lr;
            if (m2 - m1 > delta) {          // provably unique fp32 winner
                bidxs[xrow] = i1;
                atomicAdd(&hist[i1], 1u);
            } else {                        // ambiguous: exact cooperative rescan
                rlist[atomicAdd(&rcount, 1)] = xrow;
            }
        }
    }
    __syncthreads();

    // ---- cooperative rescue: whole block per row, 2 codes/thread, coalesced via Et
    for (int ri = 0; ri < rcount; ++ri) {
        const int row = rlist[ri];
        if (tid < 16) xrl[tid] = ((const float4*)(Xb + (size_t)row * DIM))[tid];
        __syncthreads();
        // exact ||x||^2, numpy pairwise 8-acc order (broadcast LDS reads)
        const float* xf = (const float*)xrl;
        float r[8];
#pragma unroll
        for (int j = 0; j < 8; ++j) { const float t = xf[j]; r[j] = t * t; }
#pragma unroll
        for (int i = 1; i < 8; ++i)
#pragma unroll
            for (int j = 0; j < 8; ++j) { const float t = xf[8 * i + j]; r[j] = fmaf(t, t, r[j]); }
        const float nxr = ((r[0] + r[1]) + (r[2] + r[3])) + ((r[4] + r[5]) + (r[6] + r[7]));

        float bmv = __builtin_inff(); int bix = 0;
        const float4* et = (const float4*)Et;
#pragma unroll
        for (int cc = 0; cc < 2; ++cc) {
            const int code = tid + 256 * cc;         // ascending within thread
            float dacc = 0.f;
#pragma unroll
            for (int g = 0; g < 16; ++g) {           // sequential k: exact reference order
                const float4 ev = et[g * 512 + code];   // lanes consecutive -> coalesced
                const float4 xv = xrl[g];
                dacc = fmaf(xv.x, ev.x, dacc);
                dacc = fmaf(xv.y, ev.y, dacc);
                dacc = fmaf(xv.z, ev.z, dacc);
                dacc = fmaf(xv.w, ev.w, dacc);
            }
            const float d2 = fmaf(-2.f, dacc, nxr) + scall[code];
            if (d2 < bmv) { bmv = d2; bix = code; }
        }
#pragma unroll
        for (int off = 1; off < 64; off <<= 1) {
            const float od = __shfl_xor(bmv, off, 64);
            const int oi = __shfl_xor(bix, off, 64);
            if (od < bmv || (od == bmv && oi < bix)) { bmv = od; bix = oi; }
        }
        if (l == 0) { rbd[w] = bmv; rbi[w] = bix; }
        __syncthreads();
        if (tid == 0) {
            float bb = rbd[0]; int ii = rbi[0];
#pragma unroll
            for (int wv = 1; wv < TPB / 64; ++wv)
                if (rbd[wv] < bb || (rbd[wv] == bb && rbi[wv] < ii)) { bb = rbd[wv]; ii = rbi[wv]; }
            bidxs[row] = ii;
            atomicAdd(&hist[ii], 1u);
        }
        __syncthreads();   // xrl/rbd reused next iteration
    }
    __syncthreads();

    // ---- epilogue: quantised_st + loss (x re-read coalesced, L3-hot; E L2-hot)
    float* outb = out + (size_t)blockIdx.x * BM * DIM;
    float ls = 0.f;
#pragma unroll
    for (int i = 0; i < 16; ++i) {
        const int gi = i * TPB + tid;
        const int row = gi >> 4;
        const int colL = gi & 15;
        const int bq = bidxs[row];
        const float4 qv = ((const float4*)E)[bq * 16 + colL];
        const float4 xv = ((const float4*)Xb)[gi];
        float4 o;
        { const float t = qv.x - xv.x; o.x = xv.x + t; const float dd = xv.x - qv.x; ls = fmaf(dd, dd, ls); }
        { const float t = qv.y - xv.y; o.y = xv.y + t; const float dd = xv.y - qv.y; ls = fmaf(dd, dd, ls); }
        { const float t = qv.z - xv.z; o.z = xv.z + t; const float dd = xv.z - qv.z; ls = fmaf(dd, dd, ls); }
        { const float t = qv.w - xv.w; o.w = xv.w + t; const float dd = xv.w - qv.w; ls = fmaf(dd, dd, ls); }
        ((float4*)outb)[gi] = o;
    }

#pragma unroll
    for (int off = 32; off > 0; off >>= 1) ls += __shfl_down(ls, off);
    if (l == 0) red[w] = (double)ls;
    __syncthreads();
    if (tid == 0) {
        double s = 0.0;
#pragma unroll
        for (int wv = 0; wv < TPB / 64; ++wv) s += red[wv];
        atomicAdd(lsum, s);
    }

    // ---- histogram flush: per-block slab (no atomics) or fallback atomic path
    if (slab) {
        unsigned int* sb = slab + (size_t)blockIdx.x * MCODE;
        for (int i = tid; i < MCODE; i += TPB) sb[i] = hist[i];
    } else {
        for (int i = tid; i < MCODE; i += TPB) {
            const unsigned int v = hist[i];
            if (v) atomicAdd(&counts[i], v);
        }
    }
}

// ---------------- mid reduce: 512 slabs -> 16 partials (no atomics)
__global__ __launch_bounds__(512) void vq_mid(const unsigned int* __restrict__ slab,
                                              unsigned int* __restrict__ mid) {
    const int t = threadIdx.x, b = blockIdx.x;
    unsigned int s = 0;
#pragma unroll 4
    for (int j = 0; j < 32; ++j) s += slab[(size_t)(b * 32 + j) * MCODE + t];
    mid[b * MCODE + t] = s;
}

// ---------------- finalize: losses + perplexity
__global__ __launch_bounds__(512) void vq_fin(const unsigned int* __restrict__ cnt,
                                              int nsl,
                                              const double* __restrict__ lsum,
                                              float* __restrict__ out3) {
    __shared__ double sred[8];
    const int t = threadIdx.x;
    unsigned int c = 0;
    for (int b = 0; b < nsl; ++b) c += cnt[b * MCODE + t];
    const double avg = (double)c / (double)ROWS;
    double term = avg * log(avg + 1e-10);
#pragma unroll
    for (int off = 32; off > 0; off >>= 1) term += __shfl_down(term, off);
    const int lane = t & 63, wid = t >> 6;
    if (lane == 0) sred[wid] = term;
    __syncthreads();
    if (t == 0) {
        double s = 0.0;
#pragma unroll
        for (int w = 0; w < 8; ++w) s += sred[w];
        const float perp = (float)exp(-s);
        const float rl = (float)(*lsum / (double)QELEMS);
        out3[0] = 0.25f * rl;   // commitment_loss
        out3[1] = rl;           // codebook_loss
        out3[2] = perp;         // perplexity
    }
}

extern "C" void kernel_launch(void* const* d_in, const int* in_sizes, int n_in,
                              void* d_out, int out_size, void* d_ws, size_t ws_size,
                              hipStream_t stream) {
    const float* X = (const float*)d_in[0];       // [32,4096,64] fp32
    const float* E = (const float*)d_in[1];       // [512,64] fp32
    float* out = (float*)d_out;                   // 8388608 + 3 floats

    char* ws = (char*)d_ws;
    double* lsum          = (double*)(ws + 0);                 //    8 B
    unsigned int* counts  = (unsigned int*)(ws + 8);           // 2048 B (fallback)
    float* cvec           = (float*)(ws + 2056);               // 2048 B
    float* consts         = (float*)(ws + 4104);               //    8 B
    _Float16* Ebf         = (_Float16*)(ws + 4112);            // 65536 B, 16B-aligned
    float* Et             = (float*)(ws + 69648);              // 131072 B, 16B-aligned
    unsigned int* slab    = (unsigned int*)(ws + 200720);      // 512*512*4 = 1 MB
    unsigned int* mid     = (unsigned int*)(ws + 200720 + 1048576);  // 16*512*4 = 32 KB
    const size_t NEED = 200720 + 1048576 + 32768;
    const bool big = ws_size >= NEED;

    vq_prep<<<1, MCODE, 0, stream>>>(E, cvec, consts, Ebf, Et, counts, lsum);
    vq_main<<<NBLK, TPB, 0, stream>>>(X, E, cvec, consts, Ebf, Et, out, counts, lsum,
                                      big ? slab : (unsigned int*)nullptr);
    if (big) {
        vq_mid<<<16, 512, 0, stream>>>(slab, mid);
        vq_fin<<<1, 512, 0, stream>>>(mid, 16, lsum, out + QELEMS);
    } else {
        vq_fin<<<1, 512, 0, stream>>>(counts, 1, lsum, out + QELEMS);
    }
}

// Round 17
// 67.989 us; speedup vs baseline: 1.9255x; 1.0089x over previous
//
#include <hip/hip_runtime.h>
#include <cmath>

#define DIM    64
#define MCODE  512
#define ROWS   131072
#define QELEMS 8388608   // 32*4096*64
#define BM     256       // rows per block (4 tiles of 64)
#define TPB    256
#define NBLK   (ROWS / BM)   // 512 -> 2 blocks/CU, all co-resident

typedef _Float16 f16x8 __attribute__((ext_vector_type(8)));
typedef float    f32x4 __attribute__((ext_vector_type(4)));

#define COMP(v, c) ((c) == 0 ? (v).x : (c) == 1 ? (v).y : (c) == 2 ? (v).z : (v).w)

// async global->LDS, 16B per lane; LDS dest = wave-uniform base + lane*16
__device__ __forceinline__ void async16(void* l, const void* g) {
    __builtin_amdgcn_global_load_lds(
        (const __attribute__((address_space(1))) unsigned int*)g,
        (__attribute__((address_space(3))) unsigned int*)l, 16, 0, 0);
}

// ---------------- prep: cvec, error-bound constants, fp16 16x16-tiled + fp32-transposed codebook
__global__ __launch_bounds__(512) void vq_prep(const float* __restrict__ E,
                                               float* __restrict__ cvec,
                                               float* __restrict__ consts,  // [0]=max||ê||, [1]=max||e-ê||
                                               _Float16* __restrict__ Ebf,
                                               float* __restrict__ Et,      // [16 granules][512 codes] float4
                                               unsigned int* __restrict__ counts,
                                               double* __restrict__ lsum) {
    __shared__ float sA[8], sB[8];
    const int m = threadIdx.x;            // 512 threads, 1 block
    counts[m] = 0u;
    if (m == 0) *lsum = 0.0;
    const float* e = E + (size_t)m * DIM;
    float r[8];
#pragma unroll
    for (int j = 0; j < 8; ++j) r[j] = e[j] * e[j];
#pragma unroll
    for (int i = 1; i < 8; ++i)
#pragma unroll
        for (int j = 0; j < 8; ++j) r[j] += e[8 * i + j] * e[8 * i + j];
    cvec[m] = ((r[0] + r[1]) + (r[2] + r[3])) + ((r[4] + r[5]) + (r[6] + r[7]));

    // transposed fp32 codebook for the coalesced rescue: Et[g*512 + code] (float4 units)
    float4* et = (float4*)Et;
#pragma unroll
    for (int g = 0; g < 16; ++g)
        et[g * 512 + m] = *(const float4*)(e + 4 * g);

    // fp16 codebook in 16x16x32 MFMA-A granule order:
    // code m: tile t=m>>4, c=m&15; k = km*32 + kg*8 + j  ->
    // granule index = ((t*2+km)*4 + kg)*16 + c
    const int t = m >> 4, c = m & 15;
    f16x8* dst = (f16x8*)Ebf;
    float en16 = 0.f, err2 = 0.f;
#pragma unroll
    for (int km = 0; km < 2; ++km)
#pragma unroll
        for (int kg = 0; kg < 4; ++kg) {
            f16x8 hv;
#pragma unroll
            for (int j = 0; j < 8; ++j) {
                const float ef = e[km * 32 + kg * 8 + j];
                const _Float16 h = (_Float16)ef;
                hv[j] = h;
                const float hf = (float)h;
                en16 = fmaf(hf, hf, en16);
                const float d = ef - hf;                 // exact (Sterbenz)
                err2 = fmaf(d, d, err2);
            }
            dst[((t * 2 + km) * 4 + kg) * 16 + c] = hv;
        }

    // wave-level max reduce (1 barrier)
#pragma unroll
    for (int off = 1; off < 64; off <<= 1) {
        en16 = fmaxf(en16, __shfl_xor(en16, off, 64));
        err2 = fmaxf(err2, __shfl_xor(err2, off, 64));
    }
    if ((m & 63) == 0) { sA[m >> 6] = en16; sB[m >> 6] = err2; }
    __syncthreads();
    if (m == 0) {
        float a = sA[0], b = sB[0];
#pragma unroll
        for (int wv = 1; wv < 8; ++wv) { a = fmaxf(a, sA[wv]); b = fmaxf(b, sB[wv]); }
        consts[0] = sqrtf(a) * 1.0001f;
        consts[1] = sqrtf(b) * 1.0001f;
    }
}

// ---------------- main: 16x16x32 f16-MFMA filter; tt-outer / 4-tile-inner (ILP-4,
// shared ds_reads). x-frags for all 4 tiles live in regs (loaded once).
__global__ __launch_bounds__(TPB, 1) void vq_main(const float* __restrict__ X,
                                                  const float* __restrict__ E,
                                                  const float* __restrict__ cvec,
                                                  const float* __restrict__ consts,
                                                  const _Float16* __restrict__ Ebf,
                                                  const float* __restrict__ Et,
                                                  float* __restrict__ out,
                                                  unsigned int* __restrict__ counts,
                                                  double* __restrict__ lsum,
                                                  unsigned int* __restrict__ slab) {
    __shared__ __align__(16) _Float16 ebf[256 * DIM];   // 32 KB: one half of codes
    __shared__ int bidxs[BM];                  // 1 KB
    __shared__ unsigned int hist[MCODE];       // 2 KB
    __shared__ float scall[MCODE];             // 2 KB
    __shared__ int rlist[BM];                  // 1 KB
    __shared__ int rcount;
    __shared__ __align__(16) float4 xrl[16];   // rescue x-row stage
    __shared__ float rbd[TPB / 64];
    __shared__ int rbi[TPB / 64];
    __shared__ double red[TPB / 64];

    const int tid = threadIdx.x;
    const int w = tid >> 6;
    const int l = tid & 63;
    const int lg = l >> 4;      // k-group / code sub-group (0..3)
    const int lr = l & 15;      // row within wave tile

    // ---- issue half-0 staging first (overlaps init + x-frag loads)
#pragma unroll
    for (int i = 0; i < 8; ++i)
        async16(((f16x8*)ebf) + i * TPB + w * 64, (const f16x8*)Ebf + i * TPB + tid);

    for (int i = tid; i < MCODE; i += TPB) { hist[i] = 0u; scall[i] = cvec[i]; }
    if (tid == 0) rcount = 0;

    const float* Xb = X + (size_t)blockIdx.x * BM * DIM;
    const f16x8* eb = (const f16x8*)ebf;

    // ---- x B-fragments for ALL 4 tiles, loaded & converted once
    f16x8 xb[4][2];
    float xn2a[4], dx2a[4];
#pragma unroll
    for (int rt = 0; rt < 4; ++rt) {
        const int xrow = rt * 64 + w * 16 + lr;
        const float4* xp = (const float4*)(Xb + xrow * DIM);
        float xn2 = 0.f, dx2 = 0.f;
#pragma unroll
        for (int km = 0; km < 2; ++km) {
            const float4 a0 = xp[km * 8 + lg * 2 + 0];
            const float4 a1 = xp[km * 8 + lg * 2 + 1];
            f16x8 v;
            v[0] = (_Float16)a0.x; v[1] = (_Float16)a0.y; v[2] = (_Float16)a0.z; v[3] = (_Float16)a0.w;
            v[4] = (_Float16)a1.x; v[5] = (_Float16)a1.y; v[6] = (_Float16)a1.z; v[7] = (_Float16)a1.w;
            xb[rt][km] = v;
            float hf, d;
            hf = (float)v[0]; d = a0.x - hf; dx2 = fmaf(d, d, dx2); xn2 = fmaf(a0.x, a0.x, xn2);
            hf = (float)v[1]; d = a0.y - hf; dx2 = fmaf(d, d, dx2); xn2 = fmaf(a0.y, a0.y, xn2);
            hf = (float)v[2]; d = a0.z - hf; dx2 = fmaf(d, d, dx2); xn2 = fmaf(a0.z, a0.z, xn2);
            hf = (float)v[3]; d = a0.w - hf; dx2 = fmaf(d, d, dx2); xn2 = fmaf(a0.w, a0.w, xn2);
            hf = (float)v[4]; d = a1.x - hf; dx2 = fmaf(d, d, dx2); xn2 = fmaf(a1.x, a1.x, xn2);
            hf = (float)v[5]; d = a1.y - hf; dx2 = fmaf(d, d, dx2); xn2 = fmaf(a1.y, a1.y, xn2);
            hf = (float)v[6]; d = a1.z - hf; dx2 = fmaf(d, d, dx2); xn2 = fmaf(a1.z, a1.z, xn2);
            hf = (float)v[7]; d = a1.w - hf; dx2 = fmaf(d, d, dx2); xn2 = fmaf(a1.w, a1.w, xn2);
        }
        xn2 += __shfl_xor(xn2, 16, 64); xn2 += __shfl_xor(xn2, 32, 64);
        dx2 += __shfl_xor(dx2, 16, 64); dx2 += __shfl_xor(dx2, 32, 64);
        xn2a[rt] = xn2; dx2a[rt] = dx2;
    }
    __syncthreads();   // staging drained (vmcnt 0), hist/scall ready

    float m1a[4], m2a[4];
    int sta[4];
#pragma unroll
    for (int rt = 0; rt < 4; ++rt) { m1a[rt] = __builtin_inff(); m2a[rt] = __builtin_inff(); sta[rt] = 0; }

    for (int h = 0; h < 2; ++h) {
        if (h) {
            __syncthreads();   // all waves done reading half 0
#pragma unroll
            for (int i = 0; i < 8; ++i)
                async16(((f16x8*)ebf) + i * TPB + w * 64,
                        (const f16x8*)Ebf + 2048 + i * TPB + tid);
            __syncthreads();   // half 1 staged
        }
#pragma unroll 4
        for (int tt = 0; tt < 16; ++tt) {
            const int t = h * 16 + tt;
            const f16x8 a0 = eb[tt * 128 + l];        // shared by all 4 tiles
            const f16x8 a1 = eb[tt * 128 + 64 + l];
            const float4 cm = *(const float4*)(scall + t * 16 + lg * 4);
            f32x4 acc[4];
#pragma unroll
            for (int rt = 0; rt < 4; ++rt) {          // 4 independent MFMA chains
                acc[rt] = (f32x4){0.f, 0.f, 0.f, 0.f};
                acc[rt] = __builtin_amdgcn_mfma_f32_16x16x32_f16(a0, xb[rt][0], acc[rt], 0, 0, 0);
                acc[rt] = __builtin_amdgcn_mfma_f32_16x16x32_f16(a1, xb[rt][1], acc[rt], 0, 0, 0);
            }
#pragma unroll
            for (int rt = 0; rt < 4; ++rt) {
                float m1 = m1a[rt], m2 = m2a[rt];
                int st = sta[rt];
#pragma unroll
                for (int r = 0; r < 4; ++r) {   // codes ascend with (t, r) within lane
                    const float v = fmaf(-2.f, acc[rt][r], COMP(cm, r));
                    m2 = __builtin_amdgcn_fmed3f(m1, v, m2);   // second-min (m1<=m2)
                    const bool b = v < m1;                     // strict < : first-min wins
                    st = b ? (t * 4 + r) : st;
                    m1 = b ? v : m1;
                }
                m1a[rt] = m1; m2a[rt] = m2; sta[rt] = st;
            }
        }
    }

    // =============== merge + commit per tile ===============
    const float2 cst = *(const float2*)consts;     // x: max||ê||, y: max||e-ê||
#pragma unroll
    for (int rt = 0; rt < 4; ++rt) {
        float m1 = m1a[rt], m2 = m2a[rt];
        int i1 = (sta[rt] >> 2) * 16 + lg * 4 + (sta[rt] & 3);
        // merge the 4 lanes holding the same row (disjoint code subsets)
#pragma unroll
        for (int off = 16; off <= 32; off <<= 1) {
            const float od = __shfl_xor(m1, off, 64);
            const int oi = __shfl_xor(i1, off, 64);
            const float os = __shfl_xor(m2, off, 64);
            m2 = fminf(fminf(m2, os), fmaxf(m1, od));
            const bool tk = od < m1 || (od == m1 && oi < i1);
            m1 = tk ? od : m1; i1 = tk ? oi : i1;
        }
        // tight rigorous ambiguity test + commit (lanes 0..15 own rows)
        const float dxn = sqrtf(dx2a[rt]) * 1.02f;
        const float xn  = sqrtf(xn2a[rt]) * 1.02f;
        const float delta = 2.1f * fmaf(dxn, cst.x, xn * cst.y) + 3.2e-7f * xn2a[rt] + 2e-6f;
        if (l < 16) {
            const int xrow = rt * 64 + w * 16 + lr;
            if (m2 - m1 > delta) {          // provably unique fp32 winner
                bidxs[xrow] = i1;
                atomicAdd(&hist[i1], 1u);
            } else {                        // ambiguous: exact cooperative rescan
                rlist[atomicAdd(&rcount, 1)] = xrow;
            }
        }
    }
    __syncthreads();

    // ---- cooperative rescue: whole block per row, 2 codes/thread, coalesced via Et
    for (int ri = 0; ri < rcount; ++ri) {
        const int row = rlist[ri];
        if (tid < 16) xrl[tid] = ((const float4*)(Xb + (size_t)row * DIM))[tid];
        __syncthreads();
        // exact ||x||^2, numpy pairwise 8-acc order (broadcast LDS reads)
        const float* xf = (const float*)xrl;
        float r[8];
#pragma unroll
        for (int j = 0; j < 8; ++j) { const float t = xf[j]; r[j] = t * t; }
#pragma unroll
        for (int i = 1; i < 8; ++i)
#pragma unroll
            for (int j = 0; j < 8; ++j) { const float t = xf[8 * i + j]; r[j] = fmaf(t, t, r[j]); }
        const float nxr = ((r[0] + r[1]) + (r[2] + r[3])) + ((r[4] + r[5]) + (r[6] + r[7]));

        float bmv = __builtin_inff(); int bix = 0;
        const float4* et = (const float4*)Et;
#pragma unroll
        for (int cc = 0; cc < 2; ++cc) {
            const int code = tid + 256 * cc;         // ascending within thread
            float dacc = 0.f;
#pragma unroll
            for (int g = 0; g < 16; ++g) {           // sequential k: exact reference order
                const float4 ev = et[g * 512 + code];   // lanes consecutive -> coalesced
                const float4 xv = xrl[g];
                dacc = fmaf(xv.x, ev.x, dacc);
                dacc = fmaf(xv.y, ev.y, dacc);
                dacc = fmaf(xv.z, ev.z, dacc);
                dacc = fmaf(xv.w, ev.w, dacc);
            }
            const float d2 = fmaf(-2.f, dacc, nxr) + scall[code];
            if (d2 < bmv) { bmv = d2; bix = code; }
        }
#pragma unroll
        for (int off = 1; off < 64; off <<= 1) {
            const float od = __shfl_xor(bmv, off, 64);
            const int oi = __shfl_xor(bix, off, 64);
            if (od < bmv || (od == bmv && oi < bix)) { bmv = od; bix = oi; }
        }
        if (l == 0) { rbd[w] = bmv; rbi[w] = bix; }
        __syncthreads();
        if (tid == 0) {
            float bb = rbd[0]; int ii = rbi[0];
#pragma unroll
            for (int wv = 1; wv < TPB / 64; ++wv)
                if (rbd[wv] < bb || (rbd[wv] == bb && rbi[wv] < ii)) { bb = rbd[wv]; ii = rbi[wv]; }
            bidxs[row] = ii;
            atomicAdd(&hist[ii], 1u);
        }
        __syncthreads();   // xrl/rbd reused next iteration
    }
    __syncthreads();

    // ---- epilogue: quantised_st + loss (x re-read coalesced, L3-hot; E L2-hot)
    float* outb = out + (size_t)blockIdx.x * BM * DIM;
    float ls = 0.f;
#pragma unroll
    for (int i = 0; i < 16; ++i) {
        const int gi = i * TPB + tid;
        const int row = gi >> 4;
        const int colL = gi & 15;
        const int bq = bidxs[row];
        const float4 qv = ((const float4*)E)[bq * 16 + colL];
        const float4 xv = ((const float4*)Xb)[gi];
        float4 o;
        { const float t = qv.x - xv.x; o.x = xv.x + t; const float dd = xv.x - qv.x; ls = fmaf(dd, dd, ls); }
        { const float t = qv.y - xv.y; o.y = xv.y + t; const float dd = xv.y - qv.y; ls = fmaf(dd, dd, ls); }
        { const float t = qv.z - xv.z; o.z = xv.z + t; const float dd = xv.z - qv.z; ls = fmaf(dd, dd, ls); }
        { const float t = qv.w - xv.w; o.w = xv.w + t; const float dd = xv.w - qv.w; ls = fmaf(dd, dd, ls); }
        ((float4*)outb)[gi] = o;
    }

#pragma unroll
    for (int off = 32; off > 0; off >>= 1) ls += __shfl_down(ls, off);
    if (l == 0) red[w] = (double)ls;
    __syncthreads();
    if (tid == 0) {
        double s = 0.0;
#pragma unroll
        for (int wv = 0; wv < TPB / 64; ++wv) s += red[wv];
        atomicAdd(lsum, s);
    }

    // ---- histogram flush: per-block slab (no atomics) or fallback atomic path
    if (slab) {
        unsigned int* sb = slab + (size_t)blockIdx.x * MCODE;
        for (int i = tid; i < MCODE; i += TPB) sb[i] = hist[i];
    } else {
        for (int i = tid; i < MCODE; i += TPB) {
            const unsigned int v = hist[i];
            if (v) atomicAdd(&counts[i], v);
        }
    }
}

// ---------------- mid reduce: 512 slabs -> 16 partials (no atomics)
__global__ __launch_bounds__(512) void vq_mid(const unsigned int* __restrict__ slab,
                                              unsigned int* __restrict__ mid) {
    const int t = threadIdx.x, b = blockIdx.x;
    unsigned int s = 0;
#pragma unroll 4
    for (int j = 0; j < 32; ++j) s += slab[(size_t)(b * 32 + j) * MCODE + t];
    mid[b * MCODE + t] = s;
}

// ---------------- finalize: losses + perplexity
__global__ __launch_bounds__(512) void vq_fin(const unsigned int* __restrict__ cnt,
                                              int nsl,
                                              const double* __restrict__ lsum,
                                              float* __restrict__ out3) {
    __shared__ double sred[8];
    const int t = threadIdx.x;
    unsigned int c = 0;
    for (int b = 0; b < nsl; ++b) c += cnt[b * MCODE + t];
    const double avg = (double)c / (double)ROWS;
    double term = avg * log(avg + 1e-10);
#pragma unroll
    for (int off = 32; off > 0; off >>= 1) term += __shfl_down(term, off);
    const int lane = t & 63, wid = t >> 6;
    if (lane == 0) sred[wid] = term;
    __syncthreads();
    if (t == 0) {
        double s = 0.0;
#pragma unroll
        for (int w = 0; w < 8; ++w) s += sred[w];
        const float perp = (float)exp(-s);
        const float rl = (float)(*lsum / (double)QELEMS);
        out3[0] = 0.25f * rl;   // commitment_loss
        out3[1] = rl;           // codebook_loss
        out3[2] = perp;         // perplexity
    }
}

extern "C" void kernel_launch(void* const* d_in, const int* in_sizes, int n_in,
                              void* d_out, int out_size, void* d_ws, size_t ws_size,
                              hipStream_t stream) {
    const float* X = (const float*)d_in[0];       // [32,4096,64] fp32
    const float* E = (const float*)d_in[1];       // [512,64] fp32
    float* out = (float*)d_out;                   // 8388608 + 3 floats

    char* ws = (char*)d_ws;
    double* lsum          = (double*)(ws + 0);                 //    8 B
    unsigned int* counts  = (unsigned int*)(ws + 8);           // 2048 B (fallback)
    float* cvec           = (float*)(ws + 2056);               // 2048 B
    float* consts         = (float*)(ws + 4104);               //    8 B
    _Float16* Ebf         = (_Float16*)(ws + 4112);            // 65536 B, 16B-aligned
    float* Et             = (float*)(ws + 69648);              // 131072 B, 16B-aligned
    unsigned int* slab    = (unsigned int*)(ws + 200720);      // 512*512*4 = 1 MB
    unsigned int* mid     = (unsigned int*)(ws + 200720 + 1048576);  // 16*512*4 = 32 KB
    const size_t NEED = 200720 + 1048576 + 32768;
    const bool big = ws_size >= NEED;

    vq_prep<<<1, MCODE, 0, stream>>>(E, cvec, consts, Ebf, Et, counts, lsum);
    vq_main<<<NBLK, TPB, 0, stream>>>(X, E, cvec, consts, Ebf, Et, out, counts, lsum,
                                      big ? slab : (unsigned int*)nullptr);
    if (big) {
        vq_mid<<<16, 512, 0, stream>>>(slab, mid);
        vq_fin<<<1, 512, 0, stream>>>(mid, 16, lsum, out + QELEMS);
    } else {
        vq_fin<<<1, 512, 0, stream>>>(counts, 1, lsum, out + QELEMS);
    }
}